// Round 8
// baseline (2454.840 us; speedup 1.0000x reference)
//
#include <hip/hip_runtime.h>
#include <cstdint>
#include <cstddef>

typedef unsigned short u16;
typedef __attribute__((__ext_vector_type__(8))) __bf16 bf16x8;
typedef __attribute__((__ext_vector_type__(4))) float f32x4;
typedef __attribute__((__ext_vector_type__(8))) unsigned short u16x8;

#define DEVI __device__ __forceinline__

constexpr int Bb = 2, Ss = 1024, Dd = 1024, Hh = 16;
constexpr int Mm = Bb * Ss;
constexpr int QKD = 128;
constexpr float EPSF = 1.1920929e-07f;
constexpr float NEG = -1e30f;
constexpr float QSCALE = 0.10206207261596577f; // 1/sqrt(96)
constexpr float LOG1E4_16 = 9.210340371976184f / 16.f;

DEVI u16 f2b(float f) {
  union { float f; uint32_t u; } a; a.f = f;
  uint32_t r = a.u + 0x7FFFu + ((a.u >> 16) & 1u);
  return (u16)(r >> 16);
}
DEVI float b2f(u16 h) {
  union { uint32_t u; float f; } a; a.u = ((uint32_t)h) << 16; return a.f;
}

// ---------------- batched fp32 -> bf16 transposed weight conversion
struct WJob { const float* src; u16* dst; int K; int N; int perm; int ntiles; };
struct WJobs { WJob j[7]; };

__global__ __launch_bounds__(256) void k_wcvt_batch(WJobs jobs, int njobs) {
  int t = blockIdx.x;
  int ji = 0;
  while (ji < njobs - 1 && t >= jobs.j[ji].ntiles) { t -= jobs.j[ji].ntiles; ++ji; }
  const float* __restrict__ src = jobs.j[ji].src;
  u16* __restrict__ dst = jobs.j[ji].dst;
  const int K = jobs.j[ji].K, N = jobs.j[ji].N, perm = jobs.j[ji].perm;
  const int ktiles = K >> 6;
  const int bk = (t % ktiles) * 64;
  const int bn = (t / ktiles) * 64;
  __shared__ float ts[64][65];
  const int tid = threadIdx.x;
  {
    int c4 = tid & 15, r = tid >> 4;
    #pragma unroll
    for (int p = 0; p < 4; ++p) {
      int row = r + p * 16;
      int col = bn + c4 * 4;
      float4 v = make_float4(0.f, 0.f, 0.f, 0.f);
      if (col < N) v = *(const float4*)(src + (size_t)(bk + row) * N + col);
      ts[row][c4 * 4 + 0] = v.x; ts[row][c4 * 4 + 1] = v.y;
      ts[row][c4 * 4 + 2] = v.z; ts[row][c4 * 4 + 3] = v.w;
    }
  }
  __syncthreads();
  {
    int k8 = tid & 7, c = tid >> 3;
    #pragma unroll
    for (int p = 0; p < 2; ++p) {
      int cc = c + p * 32;
      int gcol = bn + cc;
      int row = perm ? ((gcol < 2816) ? (gcol * 2) : ((gcol - 2816) * 2 + 1)) : gcol;
      u16x8 o;
      #pragma unroll
      for (int q = 0; q < 8; ++q) o[q] = f2b(ts[k8 * 8 + q][cc]);
      *(u16x8*)(dst + (size_t)row * K + bk + k8 * 8) = o;
    }
  }
}

// ---------------- embedding gather
__global__ void k_embed(const int* __restrict__ tok, const float* __restrict__ emb,
                        float* __restrict__ h) {
  int m = blockIdx.x;
  int t = tok[m];
  const float4* src = (const float4*)(emb + (size_t)t * Dd);
  float4* dst = (float4*)(h + (size_t)m * Dd);
  dst[threadIdx.x] = src[threadIdx.x];
}

// ---------------- rmsnorm: f32 (stride inStride) -> bf16 (stride K)
__global__ void k_rms(const float* __restrict__ in, int inStride,
                      const float* __restrict__ w, u16* __restrict__ out, int K) {
  int m = blockIdx.x;
  const float* x = in + (size_t)m * inStride;
  float ss = 0.f;
  for (int i = threadIdx.x; i < K; i += 256) { float v = x[i]; ss += v * v; }
  #pragma unroll
  for (int off = 32; off; off >>= 1) ss += __shfl_xor(ss, off);
  __shared__ float red[4];
  if ((threadIdx.x & 63) == 0) red[threadIdx.x >> 6] = ss;
  __syncthreads();
  float r = rsqrtf((red[0] + red[1] + red[2] + red[3]) / (float)K + EPSF);
  for (int i = threadIdx.x; i < K; i += 256)
    out[(size_t)m * K + i] = f2b(x[i] * r * w[i]);
}

// ---------------- bias concat for fused down-proj (288 kv | pad | 384 q)
__global__ void k_biascat(const float* __restrict__ b1, const float* __restrict__ b2,
                          float* __restrict__ out) {
  int i = blockIdx.x * 256 + threadIdx.x;
  float v = 0.f;
  if (i < 288) v = b1[i];
  else if (i >= 384) v = b2[i - 384];
  out[i] = v;
}

// ---------------- build Q and K (rope cols 64..95; Q scaled; pad to 128)
// kv is bf16 now.
__global__ void k_buildqk(const float* __restrict__ qf, const u16* __restrict__ kv,
                          const float* __restrict__ ckvq, u16* __restrict__ Q,
                          u16* __restrict__ Kb) {
  int s = blockIdx.x, bh = blockIdx.y;
  int b = bh >> 4, h = bh & 15;
  int d = threadIdx.x;
  int m = b * Ss + s;
  int j = d - 64;
  float sn = 0.f, cs = 0.f;
  if (d >= 64 && d < 96) {
    float theta = __expf(-(float)(j & 15) * LOG1E4_16);
    __sincosf((float)s * theta, &sn, &cs);
  }
  const float* qrow = qf + (size_t)m * (Hh * 96) + h * 96;
  float qv = 0.f;
  if (d < 64) qv = qrow[d];
  else if (d < 96) {
    float x = qrow[64 + j], o = qrow[64 + (j ^ 16)];
    qv = x * cs + ((j < 16) ? -o : o) * sn;
  }
  Q[((size_t)bh * Ss + s) * QKD + d] = f2b(qv * QSCALE);
  u16 kvv = 0;
  if (d < 64) kvv = kv[(size_t)m * 2048 + h * 128 + d];
  else if (d < 96) {
    const float* rr = ckvq + (size_t)m * 768 + 256;
    float x = rr[j], o = rr[j ^ 16];
    kvv = f2b(x * cs + ((j < 16) ? -o : o) * sn);
  }
  Kb[((size_t)bh * Ss + s) * QKD + d] = kvv;
}

// ---------------- build V^T (per head: [64][1024]), bf16 in -> bf16 out
__global__ void k_buildvt(const u16* __restrict__ kv, u16* __restrict__ Vt) {
  __shared__ u16 t[32][33];
  int bh = blockIdx.x, s0 = blockIdx.y * 32, d0 = blockIdx.z * 32;
  int b = bh >> 4, h = bh & 15;
  int tx = threadIdx.x, ty = threadIdx.y;
  #pragma unroll
  for (int i = ty; i < 32; i += 8) {
    int s = s0 + i, d = d0 + tx;
    t[i][tx] = kv[(size_t)(b * Ss + s) * 2048 + h * 128 + 64 + d];
  }
  __syncthreads();
  #pragma unroll
  for (int i = ty; i < 32; i += 8) {
    int d = d0 + i, s = s0 + tx;
    Vt[((size_t)bh * 64 + d) * Ss + s] = t[tx][i];
  }
}

#define GAS __attribute__((address_space(1)))
#define LAS __attribute__((address_space(3)))
DEVI void gll16(const void* g, void* l) {
  __builtin_amdgcn_global_load_lds((GAS const void*)g, (LAS void*)l, 16, 0, 0);
}
#define VMW(n) asm volatile("s_waitcnt vmcnt(" #n ")" ::: "memory")
#define FENCE asm volatile("" ::: "memory")

// ---------------- fused flash attention (causal), bf16 in/out
// grid (16 q-tiles, 32 bh), 256 thr. Double-buffered K/V with counted vmcnt.
__global__ __launch_bounds__(256) void k_flash(
    const u16* __restrict__ Qg, const u16* __restrict__ Kg,
    const u16* __restrict__ Vtg, u16* __restrict__ attn) {
  __shared__ u16 lK[2][64 * 128];
  __shared__ u16 lV[2][64 * 64];
  __shared__ u16 lP[4][16 * 64];
  const int tid = threadIdx.x;
  const int qt = blockIdx.x, bh = blockIdx.y;
  const int b = bh >> 4, h = bh & 15;
  const int lane = tid & 63, w = tid >> 6;
  const int g = lane >> 4, fr = lane & 15;
  const u16* Qh = Qg + (size_t)bh * Ss * QKD;
  const u16* Kh = Kg + (size_t)bh * Ss * QKD;
  const u16* Vh = Vtg + (size_t)bh * 64 * Ss;

  auto stageKV = [&](int buf, int kt) {
    int r = tid >> 4, c = tid & 15;
    #pragma unroll
    for (int gg = 0; gg < 4; ++gg) {
      int row = gg * 16 + r;
      const u16* src = Kh + (size_t)(kt * 64 + row) * QKD + ((c ^ (row & 7)) * 8);
      gll16(src, (u16*)lK[buf] + gg * 2048 + tid * 8);
    }
    int r2 = tid >> 3, c2 = tid & 7;
    #pragma unroll
    for (int gg = 0; gg < 2; ++gg) {
      int d = gg * 32 + r2;
      const u16* src = Vh + (size_t)d * Ss + kt * 64 + ((c2 ^ (d & 7)) * 8);
      gll16(src, (u16*)lV[buf] + gg * 2048 + tid * 8);
    }
  };

  const int q0 = qt * 64;
  bf16x8 af[4];
  const u16* qrow = Qh + (size_t)(q0 + w * 16 + fr) * QKD + g * 8;
  #pragma unroll
  for (int k4 = 0; k4 < 4; ++k4) af[k4] = *(const bf16x8*)(qrow + k4 * 32);

  f32x4 acc_o[4] = {};
  float mrow = NEG, lrow = 0.f;

  stageKV(0, 0);

  for (int kt = 0; kt <= qt; ++kt) {
    const int cur = kt & 1;
    if (kt < qt) { stageKV(cur ^ 1, kt + 1); VMW(6); }
    else { VMW(0); }
    __builtin_amdgcn_s_barrier();
    FENCE;

    f32x4 accs[4] = {};
    #pragma unroll
    for (int j = 0; j < 4; ++j) {
      #pragma unroll
      for (int k4 = 0; k4 < 4; ++k4) {
        int row = j * 16 + fr;
        int ch = (k4 * 4 + g) ^ (row & 7);
        bf16x8 kf = *(const bf16x8*)&lK[cur][row * 128 + ch * 8];
        accs[j] = __builtin_amdgcn_mfma_f32_16x16x32_bf16(kf, af[k4], accs[j], 0, 0, 0);
      }
    }

    float p[16];
    float tmax = NEG;
    #pragma unroll
    for (int j = 0; j < 4; ++j)
      #pragma unroll
      for (int r = 0; r < 4; ++r) {
        float s = accs[j][r];
        int kloc = j * 16 + 4 * g + r;
        bool valid = (kt < qt) || (kloc <= w * 16 + fr);
        s = valid ? s : NEG;
        p[j * 4 + r] = s;
        tmax = fmaxf(tmax, s);
      }
    tmax = fmaxf(tmax, __shfl_xor(tmax, 16));
    tmax = fmaxf(tmax, __shfl_xor(tmax, 32));
    float mnew = fmaxf(mrow, tmax);
    float scale = __expf(mrow - mnew);
    float tsum = 0.f;
    #pragma unroll
    for (int i = 0; i < 16; ++i) { p[i] = __expf(p[i] - mnew); tsum += p[i]; }
    tsum += __shfl_xor(tsum, 16);
    tsum += __shfl_xor(tsum, 32);
    lrow = lrow * scale + tsum;
    mrow = mnew;

    #pragma unroll
    for (int j = 0; j < 4; ++j)
      #pragma unroll
      for (int t = 0; t < 2; ++t) {
        uint32_t u = (uint32_t)f2b(p[j * 4 + 2 * t]) |
                     ((uint32_t)f2b(p[j * 4 + 2 * t + 1]) << 16);
        int kp = 8 * j + 2 * g + t;
        int ch = kp >> 2, wi = kp & 3;
        ((uint32_t*)lP[w])[fr * 32 + ((ch ^ (fr & 7)) << 2) + wi] = u;
      }

    float sc_q[4];
    #pragma unroll
    for (int r = 0; r < 4; ++r) sc_q[r] = __shfl(scale, 4 * g + r);
    #pragma unroll
    for (int j2 = 0; j2 < 4; ++j2)
      #pragma unroll
      for (int r = 0; r < 4; ++r) acc_o[j2][r] *= sc_q[r];

    #pragma unroll
    for (int ksub = 0; ksub < 2; ++ksub) {
      int chp = (4 * ksub + g) ^ (fr & 7);
      bf16x8 pa = *(const bf16x8*)&((const u16*)lP[w])[fr * 64 + chp * 8];
      #pragma unroll
      for (int j2 = 0; j2 < 4; ++j2) {
        int d = j2 * 16 + fr;
        int chv = (ksub * 4 + g) ^ (d & 7);
        bf16x8 vf = *(const bf16x8*)&lV[cur][d * 64 + chv * 8];
        acc_o[j2] = __builtin_amdgcn_mfma_f32_16x16x32_bf16(pa, vf, acc_o[j2], 0, 0, 0);
      }
    }
    FENCE;
    __builtin_amdgcn_s_barrier();
    FENCE;
  }

  float li[4];
  #pragma unroll
  for (int r = 0; r < 4; ++r) li[r] = 1.f / __shfl(lrow, 4 * g + r);
  #pragma unroll
  for (int j2 = 0; j2 < 4; ++j2)
    #pragma unroll
    for (int r = 0; r < 4; ++r) {
      int q = q0 + w * 16 + 4 * g + r;
      int d = j2 * 16 + fr;
      attn[((size_t)(b * Ss) + q) * Dd + h * 64 + d] = f2b(acc_o[j2][r] * li[r]);
    }
}

// ---------------- 128x256xK GEMM, BK=32, 8 waves, dbuf+prefetch+counted vmcnt,
// 3 blocks/CU. MODE 0: f32 C = acc + bias; MODE 1: silu-fused bf16 gate out.
template <int MODE>
__global__ __launch_bounds__(512, 6) void k_gemm256b(
    const u16* __restrict__ A, const u16* __restrict__ Bt,
    const float* __restrict__ bias, void* __restrict__ Cv,
    int N, int K) {
  __shared__ u16 lA[2][128 * 32];
  __shared__ u16 lB[2][256 * 32];
  const int tid = threadIdx.x;
  const int gx = gridDim.x;
  const int nwg = gx * gridDim.y;
  const int f = blockIdx.y * gx + blockIdx.x;
  const int f2 = (f & 7) * (nwg >> 3) + (f >> 3);
  const int bx = f2 % gx, by = f2 / gx;
  const long m0 = (long)bx * 128, n0 = (long)by * 256;
  const int lane = tid & 63, wid = tid >> 6;
  const int wm = (wid >> 2) * 64, wn = (wid & 3) * 64;
  const int fr = lane & 15, l4 = lane >> 4;
  const int sw = (fr >> 1) & 3;

  const int ra = tid >> 2;
  const int ca = ((tid & 3) ^ ((ra >> 1) & 3)) * 8;
  const u16* a0 = A + (m0 + ra) * (long)K + ca;
  const int rb = tid >> 2;
  const int cb0 = ((tid & 3) ^ ((rb >> 1) & 3)) * 8;
  const int cb1 = ((tid & 3) ^ (((rb + 128) >> 1) & 3)) * 8;
  const u16* b0 = Bt + (n0 + rb) * (long)K + cb0;
  const u16* b1 = Bt + (n0 + rb + 128) * (long)K + cb1;

  f32x4 acc[4][4] = {};
  const int NT = K >> 5;

  gll16(a0, (u16*)lA[0] + tid * 8);
  gll16(b0, (u16*)lB[0] + tid * 8);
  gll16(b1, (u16*)lB[0] + 4096 + tid * 8);

  for (int j = 0; j < NT; ++j) {
    const int cur = j & 1;
    const int kk1 = (j + 1) << 5;
    if (j + 1 < NT) {
      gll16(a0 + kk1, (u16*)lA[cur ^ 1] + tid * 8);
      gll16(b0 + kk1, (u16*)lB[cur ^ 1] + tid * 8);
      gll16(b1 + kk1, (u16*)lB[cur ^ 1] + 4096 + tid * 8);
      VMW(3);
    } else {
      VMW(0);
    }
    __builtin_amdgcn_s_barrier();
    FENCE;
    bf16x8 af[4], bfv[4];
    #pragma unroll
    for (int i = 0; i < 4; ++i)
      af[i] = *(const bf16x8*)&lA[cur][(wm + i * 16 + fr) * 32 + ((l4 ^ sw) * 8)];
    #pragma unroll
    for (int jj = 0; jj < 4; ++jj)
      bfv[jj] = *(const bf16x8*)&lB[cur][(wn + jj * 16 + fr) * 32 + ((l4 ^ sw) * 8)];
    #pragma unroll
    for (int i = 0; i < 4; ++i)
      #pragma unroll
      for (int jj = 0; jj < 4; ++jj)
        acc[i][jj] = __builtin_amdgcn_mfma_f32_16x16x32_bf16(af[i], bfv[jj], acc[i][jj], 0, 0, 0);
    FENCE;
    __builtin_amdgcn_s_barrier();
    FENCE;
  }

  const long r0 = m0 + wm + l4 * 4;
  const long c0 = n0 + wn + fr;
  if (MODE == 0) {
    float* C = (float*)Cv;
    #pragma unroll
    for (int j = 0; j < 4; ++j) {
      long col = c0 + j * 16;
      float bs = bias[col];
      #pragma unroll
      for (int i = 0; i < 4; ++i)
        #pragma unroll
        for (int r = 0; r < 4; ++r)
          C[(r0 + i * 16 + r) * (long)N + col] = acc[i][j][r] + bs;
    }
  } else {
    u16* G = (u16*)Cv;
    #pragma unroll
    for (int j = 0; j < 4; ++j) {
      long col = c0 + j * 16;
      int pcol = (int)((col & 1) ? (col >> 1) + 2816 : (col >> 1));
      float bs = bias[pcol];
      #pragma unroll
      for (int i = 0; i < 4; ++i)
        #pragma unroll
        for (int r = 0; r < 4; ++r) {
          float val = acc[i][j][r] + bs;
          float oth = __shfl_xor(val, 1);
          if (!(col & 1)) {
            float x = oth;
            float gv = val * x * (1.f / (1.f + __expf(-x)));
            G[(r0 + i * 16 + r) * 2816L + (col >> 1)] = f2b(gv);
          }
        }
    }
  }
}

// ---------------- bf16 MFMA GEMM 128xBN, dbuf+prefetch+counted vmcnt
// MODE 0: f32 C = acc + bias ; MODE 1: f32 C += acc + bias ; MODE 2: bf16 C = acc + bias
template <int MODE, int BN, bool SWZ>
__global__ __launch_bounds__(256, 6) void k_gemm(
    const u16* __restrict__ A, const u16* __restrict__ Bt,
    const float* __restrict__ bias, void* __restrict__ C,
    int N, int K, long sA, long sB, long sC) {
  __shared__ u16 lA[2][128 * 32];
  __shared__ u16 lB[2][BN * 32];
  const int tid = threadIdx.x;
  const int bz = blockIdx.z;

  int bx, by;
  if (SWZ) {
    int gx = gridDim.x;
    int nwg = gx * gridDim.y;
    int f = blockIdx.y * gx + blockIdx.x;
    int f2 = (f & 7) * (nwg >> 3) + (f >> 3);
    bx = f2 % gx; by = f2 / gx;
  } else {
    bx = blockIdx.x; by = blockIdx.y;
  }
  const long m0 = (long)bx * 128, n0 = (long)by * BN;

  const u16* Az = A + (size_t)bz * sA;
  const u16* Bz = Bt + (size_t)bz * sB;
  const int srow = tid >> 2;
  const int scol = (tid & 3) << 3;
  const u16* a0 = Az + (m0 + srow) * (long)K + scol;
  const u16* b0 = Bz + (n0 + srow) * (long)K + scol;
  const long rstep = 64L * K;

  const int lane = tid & 63, wid = tid >> 6;
  constexpr int WR = (BN == 128) ? 64 : 32;
  constexpr int MI = WR / 16;
  const int wm = (BN == 128) ? (wid >> 1) * 64 : wid * 32;
  const int wn = (BN == 128) ? (wid & 1) * 64 : 0;
  const int fr = lane & 15, kg = (lane >> 4) * 8;

  f32x4 acc[MI][4] = {};
  const int NT = K >> 5;

  // prologue: tile 0 -> buf0
  gll16(a0, (u16*)lA[0] + tid * 8);
  gll16(a0 + rstep, (u16*)lA[0] + 2048 + tid * 8);
  gll16(b0, (u16*)lB[0] + tid * 8);
  if (BN == 128) gll16(b0 + rstep, (u16*)lB[0] + 2048 + tid * 8);

  for (int j = 0; j < NT; ++j) {
    const int cur = j & 1;
    const int kk1 = (j + 1) << 5;
    if (j + 1 < NT) {
      gll16(a0 + kk1, (u16*)lA[cur ^ 1] + tid * 8);
      gll16(a0 + rstep + kk1, (u16*)lA[cur ^ 1] + 2048 + tid * 8);
      gll16(b0 + kk1, (u16*)lB[cur ^ 1] + tid * 8);
      if (BN == 128) {
        gll16(b0 + rstep + kk1, (u16*)lB[cur ^ 1] + 2048 + tid * 8);
        VMW(4);
      } else {
        VMW(3);
      }
    } else {
      VMW(0);
    }
    __builtin_amdgcn_s_barrier();
    FENCE;
    bf16x8 af[MI], bfr[4];
    #pragma unroll
    for (int i = 0; i < MI; i++) af[i] = *(const bf16x8*)&lA[cur][(wm + i * 16 + fr) * 32 + kg];
    #pragma unroll
    for (int jj = 0; jj < 4; jj++) bfr[jj] = *(const bf16x8*)&lB[cur][(wn + jj * 16 + fr) * 32 + kg];
    #pragma unroll
    for (int i = 0; i < MI; i++)
      #pragma unroll
      for (int jj = 0; jj < 4; jj++)
        acc[i][jj] = __builtin_amdgcn_mfma_f32_16x16x32_bf16(af[i], bfr[jj], acc[i][jj], 0, 0, 0);
    FENCE;
    __builtin_amdgcn_s_barrier();
    FENCE;
  }

  const int rb = wm + ((lane >> 4) << 2);
  const int cb = wn + (lane & 15);
  #pragma unroll
  for (int j = 0; j < 4; j++) {
    long gcol = n0 + cb + j * 16;
    float bs = 0.f;
    if (gcol < N) bs = bias[gcol];
    #pragma unroll
    for (int i = 0; i < MI; i++) {
      #pragma unroll
      for (int r = 0; r < 4; r++) {
        long grow = m0 + rb + i * 16 + r;
        float val = acc[i][j][r];
        if (gcol < N) {
          if (MODE == 0) {
            ((float*)C)[grow * N + gcol] = val + bs;
          } else if (MODE == 1) {
            float* p = (float*)C + grow * N + gcol; *p += val + bs;
          } else {
            ((u16*)C)[grow * N + gcol] = f2b(val + bs);
          }
        }
      }
    }
  }
}

extern "C" void kernel_launch(void* const* d_in, const int* in_sizes, int n_in,
                              void* d_out, int out_size, void* d_ws, size_t ws_size,
                              hipStream_t stream) {
  (void)in_sizes; (void)n_in; (void)out_size; (void)ws_size;
  const int*   tokens    = (const int*)  d_in[0];
  const float* embed     = (const float*)d_in[1];
  const float* w_kv_down = (const float*)d_in[2];
  const float* b_kv_down = (const float*)d_in[3];
  const float* w_q_down  = (const float*)d_in[4];
  const float* b_q_down  = (const float*)d_in[5];
  const float* w_kv_up   = (const float*)d_in[6];
  const float* b_kv_up   = (const float*)d_in[7];
  const float* w_q_up    = (const float*)d_in[8];
  const float* b_q_up    = (const float*)d_in[9];
  const float* w_o       = (const float*)d_in[10];
  const float* b_o       = (const float*)d_in[11];
  const float* kv_norm_w = (const float*)d_in[12];
  const float* q_norm_w  = (const float*)d_in[13];
  const float* norm1_w   = (const float*)d_in[14];
  const float* norm2_w   = (const float*)d_in[15];
  const float* w_in      = (const float*)d_in[16];
  const float* b_in      = (const float*)d_in[17];
  const float* w_out     = (const float*)d_in[18];
  const float* b_out     = (const float*)d_in[19];
  const float* norm_f_w  = (const float*)d_in[20];
  const float* w_head    = (const float*)d_in[21];
  const float* b_head    = (const float*)d_in[22];

  char* base = (char*)d_ws;
  size_t off = 0;
  auto alloc = [&](size_t bytes) -> void* {
    void* p = base + off;
    off += (bytes + 255) & ~(size_t)255;
    return p;
  };
  u16* warena = (u16*)alloc((size_t)32000 * 1024 * 2);
  u16* wT_dq    = warena;                        // 768 x 1024
  u16* wT_kvup  = wT_dq   + 768 * 1024;          // 2048 x 256
  u16* wT_qup   = wT_kvup + 2048 * 256;          // 1536 x 384
  u16* wT_o     = wT_qup  + 1536 * 384;          // 1024 x 1024
  u16* wT_in    = wT_o    + 1024 * 1024;         // 5632 x 1024 (pair-interleaved)
  u16* wT_out   = wT_in   + 5632 * 1024;         // 1024 x 2816

  float* h     = (float*)alloc((size_t)Mm * 1024 * 4);
  u16*   xn    = (u16*)  alloc((size_t)Mm * 1024 * 2);
  float* ckvq  = (float*)alloc((size_t)Mm * 768 * 4);
  float* bdq   = (float*)alloc(768 * 4);
  u16*   ckvn  = (u16*)  alloc((size_t)Mm * 256 * 2);
  u16*   kv    = (u16*)  alloc((size_t)Mm * 2048 * 2);   // bf16 now
  u16*   qdn   = (u16*)  alloc((size_t)Mm * 384 * 2);
  float* qf    = (float*)alloc((size_t)Mm * 1536 * 4);
  u16*   Qb    = (u16*)  alloc((size_t)32 * 1024 * QKD * 2);
  u16*   Kb    = (u16*)  alloc((size_t)32 * 1024 * QKD * 2);
  u16*   Vt    = (u16*)  alloc((size_t)32 * 64 * 1024 * 2);
  u16*   attn  = (u16*)  alloc((size_t)Mm * 1024 * 2);
  u16*   gate  = (u16*)  alloc((size_t)Mm * 2816 * 2);

  dim3 tb(32, 8);

  k_embed<<<Mm, 256, 0, stream>>>(tokens, embed, h);

  for (int l = 0; l < 4; l++) {
    WJobs jb;
    jb.j[0] = { w_kv_down + (size_t)l * 1024 * 288,  wT_dq,              1024, 288,  0, 96 };
    jb.j[1] = { w_q_down  + (size_t)l * 1024 * 384,  wT_dq + 384 * 1024, 1024, 384,  0, 96 };
    jb.j[2] = { w_kv_up   + (size_t)l * 256 * 2048,  wT_kvup,            256,  2048, 0, 128 };
    jb.j[3] = { w_q_up    + (size_t)l * 384 * 1536,  wT_qup,             384,  1536, 0, 144 };
    jb.j[4] = { w_o       + (size_t)l * 1024 * 1024, wT_o,               1024, 1024, 0, 256 };
    jb.j[5] = { w_in      + (size_t)l * 1024 * 5632, wT_in,              1024, 5632, 1, 1408 };
    jb.j[6] = { w_out     + (size_t)l * 2816 * 1024, wT_out,             2816, 1024, 0, 704 };
    k_wcvt_batch<<<2832, 256, 0, stream>>>(jb, 7);
    k_biascat<<<3, 256, 0, stream>>>(b_kv_down + l * 288, b_q_down + l * 384, bdq);

    k_rms<<<Mm, 256, 0, stream>>>(h, 1024, norm1_w + l * 1024, xn, 1024);
    k_gemm<0, 64, true><<<dim3(16, 12), 256, 0, stream>>>(xn, wT_dq, bdq,
                                                          ckvq, 768, 1024, 0, 0, 0);
    k_rms<<<Mm, 256, 0, stream>>>(ckvq, 768, kv_norm_w + l * 256, ckvn, 256);
    // kv_up writes bf16 directly (MODE 2)
    k_gemm<2, 128, true><<<dim3(16, 16), 256, 0, stream>>>(ckvn, wT_kvup, b_kv_up + l * 2048,
                                                           kv, 2048, 256, 0, 0, 0);
    k_rms<<<Mm, 256, 0, stream>>>(ckvq + 384, 768, q_norm_w + l * 384, qdn, 384);
    k_gemm<0, 128, true><<<dim3(16, 12), 256, 0, stream>>>(qdn, wT_qup, b_q_up + l * 1536,
                                                           qf, 1536, 384, 0, 0, 0);
    k_buildqk<<<dim3(Ss, 32), 128, 0, stream>>>(qf, kv, ckvq, Qb, Kb);
    k_buildvt<<<dim3(32, 32, 2), tb, 0, stream>>>(kv, Vt);
    k_flash<<<dim3(16, 32), 256, 0, stream>>>(Qb, Kb, Vt, attn);
    k_gemm<1, 64, true><<<dim3(16, 16), 256, 0, stream>>>(attn, wT_o, b_o + l * 1024,
                                                          h, 1024, 1024, 0, 0, 0);
    k_rms<<<Mm, 256, 0, stream>>>(h, 1024, norm2_w + l * 1024, xn, 1024);
    k_gemm256b<1><<<dim3(16, 22), 512, 0, stream>>>(xn, wT_in, b_in + l * 5632,
                                                    gate, 5632, 1024);
    k_gemm<1, 64, true><<<dim3(16, 16), 256, 0, stream>>>(gate, wT_out, b_out + l * 1024,
                                                          h, 1024, 2816, 0, 0, 0);
  }

  k_rms<<<Mm, 256, 0, stream>>>(h, 1024, norm_f_w, xn, 1024);
  {
    WJobs jbh;
    jbh.j[0] = { w_head, warena, 1024, 32000, 0, 8000 };
    k_wcvt_batch<<<8000, 256, 0, stream>>>(jbh, 1);
  }
  k_gemm256b<0><<<dim3(16, 125), 512, 0, stream>>>(xn, warena, b_head,
                                                   (float*)d_out, 32000, 1024);
}

// Round 9
// 1184.448 us; speedup vs baseline: 2.0726x; 2.0726x over previous
//
#include <hip/hip_runtime.h>
#include <cstdint>
#include <cstddef>

typedef unsigned short u16;
typedef __attribute__((__ext_vector_type__(8))) __bf16 bf16x8;
typedef __attribute__((__ext_vector_type__(4))) float f32x4;
typedef __attribute__((__ext_vector_type__(8))) unsigned short u16x8;

#define DEVI __device__ __forceinline__

constexpr int Bb = 2, Ss = 1024, Dd = 1024, Hh = 16;
constexpr int Mm = Bb * Ss;
constexpr int QKD = 128;
constexpr float EPSF = 1.1920929e-07f;
constexpr float NEG = -1e30f;
constexpr float QSCALE = 0.10206207261596577f; // 1/sqrt(96)
constexpr float LOG1E4_16 = 9.210340371976184f / 16.f;

DEVI u16 f2b(float f) {
  union { float f; uint32_t u; } a; a.f = f;
  uint32_t r = a.u + 0x7FFFu + ((a.u >> 16) & 1u);
  return (u16)(r >> 16);
}
DEVI float b2f(u16 h) {
  union { uint32_t u; float f; } a; a.u = ((uint32_t)h) << 16; return a.f;
}

// ---------------- batched fp32 -> bf16 transposed weight conversion
struct WJob { const float* src; u16* dst; int K; int N; int perm; int ntiles; };
struct WJobs { WJob j[7]; };

__global__ __launch_bounds__(256) void k_wcvt_batch(WJobs jobs, int njobs) {
  int t = blockIdx.x;
  int ji = 0;
  while (ji < njobs - 1 && t >= jobs.j[ji].ntiles) { t -= jobs.j[ji].ntiles; ++ji; }
  const float* __restrict__ src = jobs.j[ji].src;
  u16* __restrict__ dst = jobs.j[ji].dst;
  const int K = jobs.j[ji].K, N = jobs.j[ji].N, perm = jobs.j[ji].perm;
  const int ktiles = K >> 6;
  const int bk = (t % ktiles) * 64;
  const int bn = (t / ktiles) * 64;
  __shared__ float ts[64][65];
  const int tid = threadIdx.x;
  {
    int c4 = tid & 15, r = tid >> 4;
    #pragma unroll
    for (int p = 0; p < 4; ++p) {
      int row = r + p * 16;
      int col = bn + c4 * 4;
      float4 v = make_float4(0.f, 0.f, 0.f, 0.f);
      if (col < N) v = *(const float4*)(src + (size_t)(bk + row) * N + col);
      ts[row][c4 * 4 + 0] = v.x; ts[row][c4 * 4 + 1] = v.y;
      ts[row][c4 * 4 + 2] = v.z; ts[row][c4 * 4 + 3] = v.w;
    }
  }
  __syncthreads();
  {
    int k8 = tid & 7, c = tid >> 3;
    #pragma unroll
    for (int p = 0; p < 2; ++p) {
      int cc = c + p * 32;
      int gcol = bn + cc;
      int row = perm ? ((gcol < 2816) ? (gcol * 2) : ((gcol - 2816) * 2 + 1)) : gcol;
      u16x8 o;
      #pragma unroll
      for (int q = 0; q < 8; ++q) o[q] = f2b(ts[k8 * 8 + q][cc]);
      *(u16x8*)(dst + (size_t)row * K + bk + k8 * 8) = o;
    }
  }
}

// ---------------- embedding gather
__global__ void k_embed(const int* __restrict__ tok, const float* __restrict__ emb,
                        float* __restrict__ h) {
  int m = blockIdx.x;
  int t = tok[m];
  const float4* src = (const float4*)(emb + (size_t)t * Dd);
  float4* dst = (float4*)(h + (size_t)m * Dd);
  dst[threadIdx.x] = src[threadIdx.x];
}

// ---------------- rmsnorm: f32 (stride inStride) -> bf16 (stride K)
__global__ void k_rms(const float* __restrict__ in, int inStride,
                      const float* __restrict__ w, u16* __restrict__ out, int K) {
  int m = blockIdx.x;
  const float* x = in + (size_t)m * inStride;
  float ss = 0.f;
  for (int i = threadIdx.x; i < K; i += 256) { float v = x[i]; ss += v * v; }
  #pragma unroll
  for (int off = 32; off; off >>= 1) ss += __shfl_xor(ss, off);
  __shared__ float red[4];
  if ((threadIdx.x & 63) == 0) red[threadIdx.x >> 6] = ss;
  __syncthreads();
  float r = rsqrtf((red[0] + red[1] + red[2] + red[3]) / (float)K + EPSF);
  for (int i = threadIdx.x; i < K; i += 256)
    out[(size_t)m * K + i] = f2b(x[i] * r * w[i]);
}

// ---------------- bias concat for fused down-proj (288 kv | pad | 384 q)
__global__ void k_biascat(const float* __restrict__ b1, const float* __restrict__ b2,
                          float* __restrict__ out) {
  int i = blockIdx.x * 256 + threadIdx.x;
  float v = 0.f;
  if (i < 288) v = b1[i];
  else if (i >= 384) v = b2[i - 384];
  out[i] = v;
}

// ---------------- build Q and K (rope cols 64..95; Q scaled; pad to 128)
__global__ void k_buildqk(const float* __restrict__ qf, const u16* __restrict__ kv,
                          const float* __restrict__ ckvq, u16* __restrict__ Q,
                          u16* __restrict__ Kb) {
  int s = blockIdx.x, bh = blockIdx.y;
  int b = bh >> 4, h = bh & 15;
  int d = threadIdx.x;
  int m = b * Ss + s;
  int j = d - 64;
  float sn = 0.f, cs = 0.f;
  if (d >= 64 && d < 96) {
    float theta = __expf(-(float)(j & 15) * LOG1E4_16);
    __sincosf((float)s * theta, &sn, &cs);
  }
  const float* qrow = qf + (size_t)m * (Hh * 96) + h * 96;
  float qv = 0.f;
  if (d < 64) qv = qrow[d];
  else if (d < 96) {
    float x = qrow[64 + j], o = qrow[64 + (j ^ 16)];
    qv = x * cs + ((j < 16) ? -o : o) * sn;
  }
  Q[((size_t)bh * Ss + s) * QKD + d] = f2b(qv * QSCALE);
  u16 kvv = 0;
  if (d < 64) kvv = kv[(size_t)m * 2048 + h * 128 + d];
  else if (d < 96) {
    const float* rr = ckvq + (size_t)m * 768 + 256;
    float x = rr[j], o = rr[j ^ 16];
    kvv = f2b(x * cs + ((j < 16) ? -o : o) * sn);
  }
  Kb[((size_t)bh * Ss + s) * QKD + d] = kvv;
}

// ---------------- build V^T (per head: [64][1024]), bf16 in -> bf16 out
__global__ void k_buildvt(const u16* __restrict__ kv, u16* __restrict__ Vt) {
  __shared__ u16 t[32][33];
  int bh = blockIdx.x, s0 = blockIdx.y * 32, d0 = blockIdx.z * 32;
  int b = bh >> 4, h = bh & 15;
  int tx = threadIdx.x, ty = threadIdx.y;
  #pragma unroll
  for (int i = ty; i < 32; i += 8) {
    int s = s0 + i, d = d0 + tx;
    t[i][tx] = kv[(size_t)(b * Ss + s) * 2048 + h * 128 + 64 + d];
  }
  __syncthreads();
  #pragma unroll
  for (int i = ty; i < 32; i += 8) {
    int d = d0 + i, s = s0 + tx;
    Vt[((size_t)bh * 64 + d) * Ss + s] = t[tx][i];
  }
}

#define GAS __attribute__((address_space(1)))
#define LAS __attribute__((address_space(3)))
DEVI void gll16(const void* g, void* l) {
  __builtin_amdgcn_global_load_lds((GAS const void*)g, (LAS void*)l, 16, 0, 0);
}
#define VMW(n) asm volatile("s_waitcnt vmcnt(" #n ")" ::: "memory")
#define FENCE asm volatile("" ::: "memory")

// ---------------- fused flash attention (causal), bf16 in/out
// grid (16 q-tiles, 32 bh), 256 thr. Double-buffered K/V with counted vmcnt.
__global__ __launch_bounds__(256) void k_flash(
    const u16* __restrict__ Qg, const u16* __restrict__ Kg,
    const u16* __restrict__ Vtg, u16* __restrict__ attn) {
  __shared__ u16 lK[2][64 * 128];
  __shared__ u16 lV[2][64 * 64];
  __shared__ u16 lP[4][16 * 64];
  const int tid = threadIdx.x;
  const int qt = blockIdx.x, bh = blockIdx.y;
  const int b = bh >> 4, h = bh & 15;
  const int lane = tid & 63, w = tid >> 6;
  const int g = lane >> 4, fr = lane & 15;
  const u16* Qh = Qg + (size_t)bh * Ss * QKD;
  const u16* Kh = Kg + (size_t)bh * Ss * QKD;
  const u16* Vh = Vtg + (size_t)bh * 64 * Ss;

  auto stageKV = [&](int buf, int kt) {
    int r = tid >> 4, c = tid & 15;
    #pragma unroll
    for (int gg = 0; gg < 4; ++gg) {
      int row = gg * 16 + r;
      const u16* src = Kh + (size_t)(kt * 64 + row) * QKD + ((c ^ (row & 7)) * 8);
      gll16(src, (u16*)lK[buf] + gg * 2048 + tid * 8);
    }
    int r2 = tid >> 3, c2 = tid & 7;
    #pragma unroll
    for (int gg = 0; gg < 2; ++gg) {
      int d = gg * 32 + r2;
      const u16* src = Vh + (size_t)d * Ss + kt * 64 + ((c2 ^ (d & 7)) * 8);
      gll16(src, (u16*)lV[buf] + gg * 2048 + tid * 8);
    }
  };

  const int q0 = qt * 64;
  bf16x8 af[4];
  const u16* qrow = Qh + (size_t)(q0 + w * 16 + fr) * QKD + g * 8;
  #pragma unroll
  for (int k4 = 0; k4 < 4; ++k4) af[k4] = *(const bf16x8*)(qrow + k4 * 32);

  f32x4 acc_o[4] = {};
  float mrow = NEG, lrow = 0.f;

  stageKV(0, 0);

  for (int kt = 0; kt <= qt; ++kt) {
    const int cur = kt & 1;
    if (kt < qt) { stageKV(cur ^ 1, kt + 1); VMW(6); }
    else { VMW(0); }
    __builtin_amdgcn_s_barrier();
    FENCE;

    f32x4 accs[4] = {};
    #pragma unroll
    for (int j = 0; j < 4; ++j) {
      #pragma unroll
      for (int k4 = 0; k4 < 4; ++k4) {
        int row = j * 16 + fr;
        int ch = (k4 * 4 + g) ^ (row & 7);
        bf16x8 kf = *(const bf16x8*)&lK[cur][row * 128 + ch * 8];
        accs[j] = __builtin_amdgcn_mfma_f32_16x16x32_bf16(kf, af[k4], accs[j], 0, 0, 0);
      }
    }

    float p[16];
    float tmax = NEG;
    #pragma unroll
    for (int j = 0; j < 4; ++j)
      #pragma unroll
      for (int r = 0; r < 4; ++r) {
        float s = accs[j][r];
        int kloc = j * 16 + 4 * g + r;
        bool valid = (kt < qt) || (kloc <= w * 16 + fr);
        s = valid ? s : NEG;
        p[j * 4 + r] = s;
        tmax = fmaxf(tmax, s);
      }
    tmax = fmaxf(tmax, __shfl_xor(tmax, 16));
    tmax = fmaxf(tmax, __shfl_xor(tmax, 32));
    float mnew = fmaxf(mrow, tmax);
    float scale = __expf(mrow - mnew);
    float tsum = 0.f;
    #pragma unroll
    for (int i = 0; i < 16; ++i) { p[i] = __expf(p[i] - mnew); tsum += p[i]; }
    tsum += __shfl_xor(tsum, 16);
    tsum += __shfl_xor(tsum, 32);
    lrow = lrow * scale + tsum;
    mrow = mnew;

    #pragma unroll
    for (int j = 0; j < 4; ++j)
      #pragma unroll
      for (int t = 0; t < 2; ++t) {
        uint32_t u = (uint32_t)f2b(p[j * 4 + 2 * t]) |
                     ((uint32_t)f2b(p[j * 4 + 2 * t + 1]) << 16);
        int kp = 8 * j + 2 * g + t;
        int ch = kp >> 2, wi = kp & 3;
        ((uint32_t*)lP[w])[fr * 32 + ((ch ^ (fr & 7)) << 2) + wi] = u;
      }

    float sc_q[4];
    #pragma unroll
    for (int r = 0; r < 4; ++r) sc_q[r] = __shfl(scale, 4 * g + r);
    #pragma unroll
    for (int j2 = 0; j2 < 4; ++j2)
      #pragma unroll
      for (int r = 0; r < 4; ++r) acc_o[j2][r] *= sc_q[r];

    #pragma unroll
    for (int ksub = 0; ksub < 2; ++ksub) {
      int chp = (4 * ksub + g) ^ (fr & 7);
      bf16x8 pa = *(const bf16x8*)&((const u16*)lP[w])[fr * 64 + chp * 8];
      #pragma unroll
      for (int j2 = 0; j2 < 4; ++j2) {
        int d = j2 * 16 + fr;
        int chv = (ksub * 4 + g) ^ (d & 7);
        bf16x8 vf = *(const bf16x8*)&lV[cur][d * 64 + chv * 8];
        acc_o[j2] = __builtin_amdgcn_mfma_f32_16x16x32_bf16(pa, vf, acc_o[j2], 0, 0, 0);
      }
    }
    FENCE;
    __builtin_amdgcn_s_barrier();
    FENCE;
  }

  float li[4];
  #pragma unroll
  for (int r = 0; r < 4; ++r) li[r] = 1.f / __shfl(lrow, 4 * g + r);
  #pragma unroll
  for (int j2 = 0; j2 < 4; ++j2)
    #pragma unroll
    for (int r = 0; r < 4; ++r) {
      int q = q0 + w * 16 + 4 * g + r;
      int d = j2 * 16 + fr;
      attn[((size_t)(b * Ss) + q) * Dd + h * 64 + d] = f2b(acc_o[j2][r] * li[r]);
    }
}

// ---------------- 128x256xK GEMM, BK=32, 8 waves, dbuf+prefetch+counted vmcnt,
// 2 blocks/CU (VGPR-safe: acc=64 regs; min-waves must stay 4 — 6 spills, R8 lesson).
// MODE 0: f32 C = acc + bias; MODE 1: silu-fused bf16 gate out.
template <int MODE>
__global__ __launch_bounds__(512, 4) void k_gemm256b(
    const u16* __restrict__ A, const u16* __restrict__ Bt,
    const float* __restrict__ bias, void* __restrict__ Cv,
    int N, int K) {
  __shared__ u16 lA[2][128 * 32];
  __shared__ u16 lB[2][256 * 32];
  const int tid = threadIdx.x;
  const int gx = gridDim.x;
  const int nwg = gx * gridDim.y;
  const int f = blockIdx.y * gx + blockIdx.x;
  const int f2 = (f & 7) * (nwg >> 3) + (f >> 3);
  const int bx = f2 % gx, by = f2 / gx;
  const long m0 = (long)bx * 128, n0 = (long)by * 256;
  const int lane = tid & 63, wid = tid >> 6;
  const int wm = (wid >> 2) * 64, wn = (wid & 3) * 64;
  const int fr = lane & 15, l4 = lane >> 4;
  const int sw = (fr >> 1) & 3;

  const int ra = tid >> 2;
  const int ca = ((tid & 3) ^ ((ra >> 1) & 3)) * 8;
  const u16* a0 = A + (m0 + ra) * (long)K + ca;
  const int rb = tid >> 2;
  const int cb0 = ((tid & 3) ^ ((rb >> 1) & 3)) * 8;
  const int cb1 = ((tid & 3) ^ (((rb + 128) >> 1) & 3)) * 8;
  const u16* b0 = Bt + (n0 + rb) * (long)K + cb0;
  const u16* b1 = Bt + (n0 + rb + 128) * (long)K + cb1;

  f32x4 acc[4][4] = {};
  const int NT = K >> 5;

  gll16(a0, (u16*)lA[0] + tid * 8);
  gll16(b0, (u16*)lB[0] + tid * 8);
  gll16(b1, (u16*)lB[0] + 4096 + tid * 8);

  for (int j = 0; j < NT; ++j) {
    const int cur = j & 1;
    const int kk1 = (j + 1) << 5;
    if (j + 1 < NT) {
      gll16(a0 + kk1, (u16*)lA[cur ^ 1] + tid * 8);
      gll16(b0 + kk1, (u16*)lB[cur ^ 1] + tid * 8);
      gll16(b1 + kk1, (u16*)lB[cur ^ 1] + 4096 + tid * 8);
      VMW(3);
    } else {
      VMW(0);
    }
    __builtin_amdgcn_s_barrier();
    FENCE;
    bf16x8 af[4], bfv[4];
    #pragma unroll
    for (int i = 0; i < 4; ++i)
      af[i] = *(const bf16x8*)&lA[cur][(wm + i * 16 + fr) * 32 + ((l4 ^ sw) * 8)];
    #pragma unroll
    for (int jj = 0; jj < 4; ++jj)
      bfv[jj] = *(const bf16x8*)&lB[cur][(wn + jj * 16 + fr) * 32 + ((l4 ^ sw) * 8)];
    #pragma unroll
    for (int i = 0; i < 4; ++i)
      #pragma unroll
      for (int jj = 0; jj < 4; ++jj)
        acc[i][jj] = __builtin_amdgcn_mfma_f32_16x16x32_bf16(af[i], bfv[jj], acc[i][jj], 0, 0, 0);
    FENCE;
    __builtin_amdgcn_s_barrier();
    FENCE;
  }

  const long r0 = m0 + wm + l4 * 4;
  const long c0 = n0 + wn + fr;
  if (MODE == 0) {
    float* C = (float*)Cv;
    #pragma unroll
    for (int j = 0; j < 4; ++j) {
      long col = c0 + j * 16;
      float bs = bias[col];
      #pragma unroll
      for (int i = 0; i < 4; ++i)
        #pragma unroll
        for (int r = 0; r < 4; ++r)
          C[(r0 + i * 16 + r) * (long)N + col] = acc[i][j][r] + bs;
    }
  } else {
    u16* G = (u16*)Cv;
    #pragma unroll
    for (int j = 0; j < 4; ++j) {
      long col = c0 + j * 16;
      int pcol = (int)((col & 1) ? (col >> 1) + 2816 : (col >> 1));
      float bs = bias[pcol];
      #pragma unroll
      for (int i = 0; i < 4; ++i)
        #pragma unroll
        for (int r = 0; r < 4; ++r) {
          float val = acc[i][j][r] + bs;
          float oth = __shfl_xor(val, 1);
          if (!(col & 1)) {
            float x = oth;
            float gv = val * x * (1.f / (1.f + __expf(-x)));
            G[(r0 + i * 16 + r) * 2816L + (col >> 1)] = f2b(gv);
          }
        }
    }
  }
}

// ---------------- bf16 MFMA GEMM 128xBN, dbuf+prefetch+counted vmcnt
// MODE 0: f32 C = acc + bias ; MODE 1: f32 C += acc + bias ; MODE 2: bf16 C = acc + bias
template <int MODE, int BN, bool SWZ>
__global__ __launch_bounds__(256, 4) void k_gemm(
    const u16* __restrict__ A, const u16* __restrict__ Bt,
    const float* __restrict__ bias, void* __restrict__ C,
    int N, int K, long sA, long sB, long sC) {
  __shared__ u16 lA[2][128 * 32];
  __shared__ u16 lB[2][BN * 32];
  const int tid = threadIdx.x;
  const int bz = blockIdx.z;

  int bx, by;
  if (SWZ) {
    int gx = gridDim.x;
    int nwg = gx * gridDim.y;
    int f = blockIdx.y * gx + blockIdx.x;
    int f2 = (f & 7) * (nwg >> 3) + (f >> 3);
    bx = f2 % gx; by = f2 / gx;
  } else {
    bx = blockIdx.x; by = blockIdx.y;
  }
  const long m0 = (long)bx * 128, n0 = (long)by * BN;

  const u16* Az = A + (size_t)bz * sA;
  const u16* Bz = Bt + (size_t)bz * sB;
  const int srow = tid >> 2;
  const int scol = (tid & 3) << 3;
  const u16* a0 = Az + (m0 + srow) * (long)K + scol;
  const u16* b0 = Bz + (n0 + srow) * (long)K + scol;
  const long rstep = 64L * K;

  const int lane = tid & 63, wid = tid >> 6;
  constexpr int WR = (BN == 128) ? 64 : 32;
  constexpr int MI = WR / 16;
  const int wm = (BN == 128) ? (wid >> 1) * 64 : wid * 32;
  const int wn = (BN == 128) ? (wid & 1) * 64 : 0;
  const int fr = lane & 15, kg = (lane >> 4) * 8;

  f32x4 acc[MI][4] = {};
  const int NT = K >> 5;

  gll16(a0, (u16*)lA[0] + tid * 8);
  gll16(a0 + rstep, (u16*)lA[0] + 2048 + tid * 8);
  gll16(b0, (u16*)lB[0] + tid * 8);
  if (BN == 128) gll16(b0 + rstep, (u16*)lB[0] + 2048 + tid * 8);

  for (int j = 0; j < NT; ++j) {
    const int cur = j & 1;
    const int kk1 = (j + 1) << 5;
    if (j + 1 < NT) {
      gll16(a0 + kk1, (u16*)lA[cur ^ 1] + tid * 8);
      gll16(a0 + rstep + kk1, (u16*)lA[cur ^ 1] + 2048 + tid * 8);
      gll16(b0 + kk1, (u16*)lB[cur ^ 1] + tid * 8);
      if (BN == 128) {
        gll16(b0 + rstep + kk1, (u16*)lB[cur ^ 1] + 2048 + tid * 8);
        VMW(4);
      } else {
        VMW(3);
      }
    } else {
      VMW(0);
    }
    __builtin_amdgcn_s_barrier();
    FENCE;
    bf16x8 af[MI], bfr[4];
    #pragma unroll
    for (int i = 0; i < MI; i++) af[i] = *(const bf16x8*)&lA[cur][(wm + i * 16 + fr) * 32 + kg];
    #pragma unroll
    for (int jj = 0; jj < 4; jj++) bfr[jj] = *(const bf16x8*)&lB[cur][(wn + jj * 16 + fr) * 32 + kg];
    #pragma unroll
    for (int i = 0; i < MI; i++)
      #pragma unroll
      for (int jj = 0; jj < 4; jj++)
        acc[i][jj] = __builtin_amdgcn_mfma_f32_16x16x32_bf16(af[i], bfr[jj], acc[i][jj], 0, 0, 0);
    FENCE;
    __builtin_amdgcn_s_barrier();
    FENCE;
  }

  const int rb = wm + ((lane >> 4) << 2);
  const int cb = wn + (lane & 15);
  #pragma unroll
  for (int j = 0; j < 4; j++) {
    long gcol = n0 + cb + j * 16;
    float bs = 0.f;
    if (gcol < N) bs = bias[gcol];
    #pragma unroll
    for (int i = 0; i < MI; i++) {
      #pragma unroll
      for (int r = 0; r < 4; r++) {
        long grow = m0 + rb + i * 16 + r;
        float val = acc[i][j][r];
        if (gcol < N) {
          if (MODE == 0) {
            ((float*)C)[grow * N + gcol] = val + bs;
          } else if (MODE == 1) {
            float* p = (float*)C + grow * N + gcol; *p += val + bs;
          } else {
            ((u16*)C)[grow * N + gcol] = f2b(val + bs);
          }
        }
      }
    }
  }
}

extern "C" void kernel_launch(void* const* d_in, const int* in_sizes, int n_in,
                              void* d_out, int out_size, void* d_ws, size_t ws_size,
                              hipStream_t stream) {
  (void)in_sizes; (void)n_in; (void)out_size; (void)ws_size;
  const int*   tokens    = (const int*)  d_in[0];
  const float* embed     = (const float*)d_in[1];
  const float* w_kv_down = (const float*)d_in[2];
  const float* b_kv_down = (const float*)d_in[3];
  const float* w_q_down  = (const float*)d_in[4];
  const float* b_q_down  = (const float*)d_in[5];
  const float* w_kv_up   = (const float*)d_in[6];
  const float* b_kv_up   = (const float*)d_in[7];
  const float* w_q_up    = (const float*)d_in[8];
  const float* b_q_up    = (const float*)d_in[9];
  const float* w_o       = (const float*)d_in[10];
  const float* b_o       = (const float*)d_in[11];
  const float* kv_norm_w = (const float*)d_in[12];
  const float* q_norm_w  = (const float*)d_in[13];
  const float* norm1_w   = (const float*)d_in[14];
  const float* norm2_w   = (const float*)d_in[15];
  const float* w_in      = (const float*)d_in[16];
  const float* b_in      = (const float*)d_in[17];
  const float* w_out     = (const float*)d_in[18];
  const float* b_out     = (const float*)d_in[19];
  const float* norm_f_w  = (const float*)d_in[20];
  const float* w_head    = (const float*)d_in[21];
  const float* b_head    = (const float*)d_in[22];

  char* base = (char*)d_ws;
  size_t off = 0;
  auto alloc = [&](size_t bytes) -> void* {
    void* p = base + off;
    off += (bytes + 255) & ~(size_t)255;
    return p;
  };
  u16* warena = (u16*)alloc((size_t)32000 * 1024 * 2);
  u16* wT_dq    = warena;                        // 768 x 1024
  u16* wT_kvup  = wT_dq   + 768 * 1024;          // 2048 x 256
  u16* wT_qup   = wT_kvup + 2048 * 256;          // 1536 x 384
  u16* wT_o     = wT_qup  + 1536 * 384;          // 1024 x 1024
  u16* wT_in    = wT_o    + 1024 * 1024;         // 5632 x 1024 (pair-interleaved)
  u16* wT_out   = wT_in   + 5632 * 1024;         // 1024 x 2816

  float* h     = (float*)alloc((size_t)Mm * 1024 * 4);
  u16*   xn    = (u16*)  alloc((size_t)Mm * 1024 * 2);
  float* ckvq  = (float*)alloc((size_t)Mm * 768 * 4);
  float* bdq   = (float*)alloc(768 * 4);
  u16*   ckvn  = (u16*)  alloc((size_t)Mm * 256 * 2);
  u16*   kv    = (u16*)  alloc((size_t)Mm * 2048 * 2);
  u16*   qdn   = (u16*)  alloc((size_t)Mm * 384 * 2);
  float* qf    = (float*)alloc((size_t)Mm * 1536 * 4);
  u16*   Qb    = (u16*)  alloc((size_t)32 * 1024 * QKD * 2);
  u16*   Kb    = (u16*)  alloc((size_t)32 * 1024 * QKD * 2);
  u16*   Vt    = (u16*)  alloc((size_t)32 * 64 * 1024 * 2);
  u16*   attn  = (u16*)  alloc((size_t)Mm * 1024 * 2);
  u16*   gate  = (u16*)  alloc((size_t)Mm * 2816 * 2);

  dim3 tb(32, 8);

  k_embed<<<Mm, 256, 0, stream>>>(tokens, embed, h);

  for (int l = 0; l < 4; l++) {
    WJobs jb;
    jb.j[0] = { w_kv_down + (size_t)l * 1024 * 288,  wT_dq,              1024, 288,  0, 96 };
    jb.j[1] = { w_q_down  + (size_t)l * 1024 * 384,  wT_dq + 384 * 1024, 1024, 384,  0, 96 };
    jb.j[2] = { w_kv_up   + (size_t)l * 256 * 2048,  wT_kvup,            256,  2048, 0, 128 };
    jb.j[3] = { w_q_up    + (size_t)l * 384 * 1536,  wT_qup,             384,  1536, 0, 144 };
    jb.j[4] = { w_o       + (size_t)l * 1024 * 1024, wT_o,               1024, 1024, 0, 256 };
    jb.j[5] = { w_in      + (size_t)l * 1024 * 5632, wT_in,              1024, 5632, 1, 1408 };
    jb.j[6] = { w_out     + (size_t)l * 2816 * 1024, wT_out,             2816, 1024, 0, 704 };
    k_wcvt_batch<<<2832, 256, 0, stream>>>(jb, 7);
    k_biascat<<<3, 256, 0, stream>>>(b_kv_down + l * 288, b_q_down + l * 384, bdq);

    k_rms<<<Mm, 256, 0, stream>>>(h, 1024, norm1_w + l * 1024, xn, 1024);
    k_gemm<0, 64, true><<<dim3(16, 12), 256, 0, stream>>>(xn, wT_dq, bdq,
                                                          ckvq, 768, 1024, 0, 0, 0);
    k_rms<<<Mm, 256, 0, stream>>>(ckvq, 768, kv_norm_w + l * 256, ckvn, 256);
    k_gemm<2, 128, true><<<dim3(16, 16), 256, 0, stream>>>(ckvn, wT_kvup, b_kv_up + l * 2048,
                                                           kv, 2048, 256, 0, 0, 0);
    k_rms<<<Mm, 256, 0, stream>>>(ckvq + 384, 768, q_norm_w + l * 384, qdn, 384);
    k_gemm<0, 128, true><<<dim3(16, 12), 256, 0, stream>>>(qdn, wT_qup, b_q_up + l * 1536,
                                                           qf, 1536, 384, 0, 0, 0);
    k_buildqk<<<dim3(Ss, 32), 128, 0, stream>>>(qf, kv, ckvq, Qb, Kb);
    k_buildvt<<<dim3(32, 32, 2), tb, 0, stream>>>(kv, Vt);
    k_flash<<<dim3(16, 32), 256, 0, stream>>>(Qb, Kb, Vt, attn);
    k_gemm<1, 64, true><<<dim3(16, 16), 256, 0, stream>>>(attn, wT_o, b_o + l * 1024,
                                                          h, 1024, 1024, 0, 0, 0);
    k_rms<<<Mm, 256, 0, stream>>>(h, 1024, norm2_w + l * 1024, xn, 1024);
    k_gemm256b<1><<<dim3(16, 22), 512, 0, stream>>>(xn, wT_in, b_in + l * 5632,
                                                    gate, 5632, 1024);
    k_gemm<1, 64, true><<<dim3(16, 16), 256, 0, stream>>>(gate, wT_out, b_out + l * 1024,
                                                          h, 1024, 2816, 0, 0, 0);
  }

  k_rms<<<Mm, 256, 0, stream>>>(h, 1024, norm_f_w, xn, 1024);
  {
    WJobs jbh;
    jbh.j[0] = { w_head, warena, 1024, 32000, 0, 8000 };
    k_wcvt_batch<<<8000, 256, 0, stream>>>(jbh, 1);
  }
  k_gemm256b<0><<<dim3(16, 125), 512, 0, stream>>>(xn, warena, b_head,
                                                   (float*)d_out, 32000, 1024);
}

// Round 11
// 1070.154 us; speedup vs baseline: 2.2939x; 1.1068x over previous
//
#include <hip/hip_runtime.h>
#include <cstdint>
#include <cstddef>

typedef unsigned short u16;
typedef __attribute__((__ext_vector_type__(8))) __bf16 bf16x8;
typedef __attribute__((__ext_vector_type__(4))) float f32x4;
typedef __attribute__((__ext_vector_type__(8))) unsigned short u16x8;

#define DEVI __device__ __forceinline__

constexpr int Bb = 2, Ss = 1024, Dd = 1024, Hh = 16;
constexpr int Mm = Bb * Ss;
constexpr int QKD = 128;
constexpr float EPSF = 1.1920929e-07f;
constexpr float NEG = -1e30f;
constexpr float QSCALE = 0.10206207261596577f; // 1/sqrt(96)
constexpr float LOG1E4_16 = 9.210340371976184f / 16.f;

DEVI u16 f2b(float f) {
  union { float f; uint32_t u; } a; a.f = f;
  uint32_t r = a.u + 0x7FFFu + ((a.u >> 16) & 1u);
  return (u16)(r >> 16);
}
DEVI float b2f(u16 h) {
  union { uint32_t u; float f; } a; a.u = ((uint32_t)h) << 16; return a.f;
}

// ---------------- batched fp32 -> bf16 transposed weight conversion
struct WJob { const float* src; u16* dst; int K; int N; int perm; int ntiles; };
struct WJobs { WJob j[7]; };

__global__ __launch_bounds__(256) void k_wcvt_batch(WJobs jobs, int njobs) {
  int t = blockIdx.x;
  int ji = 0;
  while (ji < njobs - 1 && t >= jobs.j[ji].ntiles) { t -= jobs.j[ji].ntiles; ++ji; }
  const float* __restrict__ src = jobs.j[ji].src;
  u16* __restrict__ dst = jobs.j[ji].dst;
  const int K = jobs.j[ji].K, N = jobs.j[ji].N, perm = jobs.j[ji].perm;
  const int ktiles = K >> 6;
  const int bk = (t % ktiles) * 64;
  const int bn = (t / ktiles) * 64;
  __shared__ float ts[64][65];
  const int tid = threadIdx.x;
  {
    int c4 = tid & 15, r = tid >> 4;
    #pragma unroll
    for (int p = 0; p < 4; ++p) {
      int row = r + p * 16;
      int col = bn + c4 * 4;
      float4 v = make_float4(0.f, 0.f, 0.f, 0.f);
      if (col < N) v = *(const float4*)(src + (size_t)(bk + row) * N + col);
      ts[row][c4 * 4 + 0] = v.x; ts[row][c4 * 4 + 1] = v.y;
      ts[row][c4 * 4 + 2] = v.z; ts[row][c4 * 4 + 3] = v.w;
    }
  }
  __syncthreads();
  {
    int k8 = tid & 7, c = tid >> 3;
    #pragma unroll
    for (int p = 0; p < 2; ++p) {
      int cc = c + p * 32;
      int gcol = bn + cc;
      int row = perm ? ((gcol < 2816) ? (gcol * 2) : ((gcol - 2816) * 2 + 1)) : gcol;
      u16x8 o;
      #pragma unroll
      for (int q = 0; q < 8; ++q) o[q] = f2b(ts[k8 * 8 + q][cc]);
      *(u16x8*)(dst + (size_t)row * K + bk + k8 * 8) = o;
    }
  }
}

// ---------------- embedding gather
__global__ void k_embed(const int* __restrict__ tok, const float* __restrict__ emb,
                        float* __restrict__ h) {
  int m = blockIdx.x;
  int t = tok[m];
  const float4* src = (const float4*)(emb + (size_t)t * Dd);
  float4* dst = (float4*)(h + (size_t)m * Dd);
  dst[threadIdx.x] = src[threadIdx.x];
}

// ---------------- rmsnorm: f32 (stride inStride) -> bf16 (stride K)
__global__ void k_rms(const float* __restrict__ in, int inStride,
                      const float* __restrict__ w, u16* __restrict__ out, int K) {
  int m = blockIdx.x;
  const float* x = in + (size_t)m * inStride;
  float ss = 0.f;
  for (int i = threadIdx.x; i < K; i += 256) { float v = x[i]; ss += v * v; }
  #pragma unroll
  for (int off = 32; off; off >>= 1) ss += __shfl_xor(ss, off);
  __shared__ float red[4];
  if ((threadIdx.x & 63) == 0) red[threadIdx.x >> 6] = ss;
  __syncthreads();
  float r = rsqrtf((red[0] + red[1] + red[2] + red[3]) / (float)K + EPSF);
  for (int i = threadIdx.x; i < K; i += 256)
    out[(size_t)m * K + i] = f2b(x[i] * r * w[i]);
}

// ---------------- bias concat for fused down-proj (288 kv | pad | 384 q)
__global__ void k_biascat(const float* __restrict__ b1, const float* __restrict__ b2,
                          float* __restrict__ out) {
  int i = blockIdx.x * 256 + threadIdx.x;
  float v = 0.f;
  if (i < 288) v = b1[i];
  else if (i >= 384) v = b2[i - 384];
  out[i] = v;
}

// ---------------- build Q and K (rope cols 64..95; Q scaled; pad to 128)
__global__ void k_buildqk(const float* __restrict__ qf, const u16* __restrict__ kv,
                          const float* __restrict__ ckvq, u16* __restrict__ Q,
                          u16* __restrict__ Kb) {
  int s = blockIdx.x, bh = blockIdx.y;
  int b = bh >> 4, h = bh & 15;
  int d = threadIdx.x;
  int m = b * Ss + s;
  int j = d - 64;
  float sn = 0.f, cs = 0.f;
  if (d >= 64 && d < 96) {
    float theta = __expf(-(float)(j & 15) * LOG1E4_16);
    __sincosf((float)s * theta, &sn, &cs);
  }
  const float* qrow = qf + (size_t)m * (Hh * 96) + h * 96;
  float qv = 0.f;
  if (d < 64) qv = qrow[d];
  else if (d < 96) {
    float x = qrow[64 + j], o = qrow[64 + (j ^ 16)];
    qv = x * cs + ((j < 16) ? -o : o) * sn;
  }
  Q[((size_t)bh * Ss + s) * QKD + d] = f2b(qv * QSCALE);
  u16 kvv = 0;
  if (d < 64) kvv = kv[(size_t)m * 2048 + h * 128 + d];
  else if (d < 96) {
    const float* rr = ckvq + (size_t)m * 768 + 256;
    float x = rr[j], o = rr[j ^ 16];
    kvv = f2b(x * cs + ((j < 16) ? -o : o) * sn);
  }
  Kb[((size_t)bh * Ss + s) * QKD + d] = kvv;
}

// ---------------- build V^T (per head: [64][1024]), bf16 in -> bf16 out
__global__ void k_buildvt(const u16* __restrict__ kv, u16* __restrict__ Vt) {
  __shared__ u16 t[32][33];
  int bh = blockIdx.x, s0 = blockIdx.y * 32, d0 = blockIdx.z * 32;
  int b = bh >> 4, h = bh & 15;
  int tx = threadIdx.x, ty = threadIdx.y;
  #pragma unroll
  for (int i = ty; i < 32; i += 8) {
    int s = s0 + i, d = d0 + tx;
    t[i][tx] = kv[(size_t)(b * Ss + s) * 2048 + h * 128 + 64 + d];
  }
  __syncthreads();
  #pragma unroll
  for (int i = ty; i < 32; i += 8) {
    int d = d0 + i, s = s0 + tx;
    Vt[((size_t)bh * 64 + d) * Ss + s] = t[tx][i];
  }
}

#define GAS __attribute__((address_space(1)))
#define LAS __attribute__((address_space(3)))
DEVI void gll16(const void* g, void* l) {
  __builtin_amdgcn_global_load_lds((GAS const void*)g, (LAS void*)l, 16, 0, 0);
}
#define VMW(n) asm volatile("s_waitcnt vmcnt(" #n ")" ::: "memory")
#define FENCE asm volatile("" ::: "memory")

// ---------------- fused flash attention (causal), bf16 in/out
__global__ __launch_bounds__(256) void k_flash(
    const u16* __restrict__ Qg, const u16* __restrict__ Kg,
    const u16* __restrict__ Vtg, u16* __restrict__ attn) {
  __shared__ u16 lK[2][64 * 128];
  __shared__ u16 lV[2][64 * 64];
  __shared__ u16 lP[4][16 * 64];
  const int tid = threadIdx.x;
  const int qt = blockIdx.x, bh = blockIdx.y;
  const int b = bh >> 4, h = bh & 15;
  const int lane = tid & 63, w = tid >> 6;
  const int g = lane >> 4, fr = lane & 15;
  const u16* Qh = Qg + (size_t)bh * Ss * QKD;
  const u16* Kh = Kg + (size_t)bh * Ss * QKD;
  const u16* Vh = Vtg + (size_t)bh * 64 * Ss;

  auto stageKV = [&](int buf, int kt) {
    int r = tid >> 4, c = tid & 15;
    #pragma unroll
    for (int gg = 0; gg < 4; ++gg) {
      int row = gg * 16 + r;
      const u16* src = Kh + (size_t)(kt * 64 + row) * QKD + ((c ^ (row & 7)) * 8);
      gll16(src, (u16*)lK[buf] + gg * 2048 + tid * 8);
    }
    int r2 = tid >> 3, c2 = tid & 7;
    #pragma unroll
    for (int gg = 0; gg < 2; ++gg) {
      int d = gg * 32 + r2;
      const u16* src = Vh + (size_t)d * Ss + kt * 64 + ((c2 ^ (d & 7)) * 8);
      gll16(src, (u16*)lV[buf] + gg * 2048 + tid * 8);
    }
  };

  const int q0 = qt * 64;
  bf16x8 af[4];
  const u16* qrow = Qh + (size_t)(q0 + w * 16 + fr) * QKD + g * 8;
  #pragma unroll
  for (int k4 = 0; k4 < 4; ++k4) af[k4] = *(const bf16x8*)(qrow + k4 * 32);

  f32x4 acc_o[4] = {};
  float mrow = NEG, lrow = 0.f;

  stageKV(0, 0);

  for (int kt = 0; kt <= qt; ++kt) {
    const int cur = kt & 1;
    if (kt < qt) { stageKV(cur ^ 1, kt + 1); VMW(6); }
    else { VMW(0); }
    __builtin_amdgcn_s_barrier();
    FENCE;

    f32x4 accs[4] = {};
    #pragma unroll
    for (int j = 0; j < 4; ++j) {
      #pragma unroll
      for (int k4 = 0; k4 < 4; ++k4) {
        int row = j * 16 + fr;
        int ch = (k4 * 4 + g) ^ (row & 7);
        bf16x8 kf = *(const bf16x8*)&lK[cur][row * 128 + ch * 8];
        accs[j] = __builtin_amdgcn_mfma_f32_16x16x32_bf16(kf, af[k4], accs[j], 0, 0, 0);
      }
    }

    float p[16];
    float tmax = NEG;
    #pragma unroll
    for (int j = 0; j < 4; ++j)
      #pragma unroll
      for (int r = 0; r < 4; ++r) {
        float s = accs[j][r];
        int kloc = j * 16 + 4 * g + r;
        bool valid = (kt < qt) || (kloc <= w * 16 + fr);
        s = valid ? s : NEG;
        p[j * 4 + r] = s;
        tmax = fmaxf(tmax, s);
      }
    tmax = fmaxf(tmax, __shfl_xor(tmax, 16));
    tmax = fmaxf(tmax, __shfl_xor(tmax, 32));
    float mnew = fmaxf(mrow, tmax);
    float scale = __expf(mrow - mnew);
    float tsum = 0.f;
    #pragma unroll
    for (int i = 0; i < 16; ++i) { p[i] = __expf(p[i] - mnew); tsum += p[i]; }
    tsum += __shfl_xor(tsum, 16);
    tsum += __shfl_xor(tsum, 32);
    lrow = lrow * scale + tsum;
    mrow = mnew;

    #pragma unroll
    for (int j = 0; j < 4; ++j)
      #pragma unroll
      for (int t = 0; t < 2; ++t) {
        uint32_t u = (uint32_t)f2b(p[j * 4 + 2 * t]) |
                     ((uint32_t)f2b(p[j * 4 + 2 * t + 1]) << 16);
        int kp = 8 * j + 2 * g + t;
        int ch = kp >> 2, wi = kp & 3;
        ((uint32_t*)lP[w])[fr * 32 + ((ch ^ (fr & 7)) << 2) + wi] = u;
      }

    float sc_q[4];
    #pragma unroll
    for (int r = 0; r < 4; ++r) sc_q[r] = __shfl(scale, 4 * g + r);
    #pragma unroll
    for (int j2 = 0; j2 < 4; ++j2)
      #pragma unroll
      for (int r = 0; r < 4; ++r) acc_o[j2][r] *= sc_q[r];

    #pragma unroll
    for (int ksub = 0; ksub < 2; ++ksub) {
      int chp = (4 * ksub + g) ^ (fr & 7);
      bf16x8 pa = *(const bf16x8*)&((const u16*)lP[w])[fr * 64 + chp * 8];
      #pragma unroll
      for (int j2 = 0; j2 < 4; ++j2) {
        int d = j2 * 16 + fr;
        int chv = (ksub * 4 + g) ^ (d & 7);
        bf16x8 vf = *(const bf16x8*)&lV[cur][d * 64 + chv * 8];
        acc_o[j2] = __builtin_amdgcn_mfma_f32_16x16x32_bf16(pa, vf, acc_o[j2], 0, 0, 0);
      }
    }
    FENCE;
    __builtin_amdgcn_s_barrier();
    FENCE;
  }

  float li[4];
  #pragma unroll
  for (int r = 0; r < 4; ++r) li[r] = 1.f / __shfl(lrow, 4 * g + r);
  #pragma unroll
  for (int j2 = 0; j2 < 4; ++j2)
    #pragma unroll
    for (int r = 0; r < 4; ++r) {
      int q = q0 + w * 16 + 4 * g + r;
      int d = j2 * 16 + fr;
      attn[((size_t)(b * Ss) + q) * Dd + h * 64 + d] = f2b(acc_o[j2][r] * li[r]);
    }
}

// ---------------- 128x256xK GEMM for the head (proven: 2 blocks/CU).
__global__ __launch_bounds__(512, 4) void k_gemm256b(
    const u16* __restrict__ A, const u16* __restrict__ Bt,
    const float* __restrict__ bias, float* __restrict__ C,
    int N, int K) {
  __shared__ u16 lA[2][128 * 32];
  __shared__ u16 lB[2][256 * 32];
  const int tid = threadIdx.x;
  const int gx = gridDim.x;
  const int nwg = gx * gridDim.y;
  const int f = blockIdx.y * gx + blockIdx.x;
  const int f2 = (f & 7) * (nwg >> 3) + (f >> 3);
  const int bx = f2 % gx, by = f2 / gx;
  const long m0 = (long)bx * 128, n0 = (long)by * 256;
  const int lane = tid & 63, wid = tid >> 6;
  const int wm = (wid >> 2) * 64, wn = (wid & 3) * 64;
  const int fr = lane & 15, l4 = lane >> 4;
  const int sw = (fr >> 1) & 3;

  const int ra = tid >> 2;
  const int ca = ((tid & 3) ^ ((ra >> 1) & 3)) * 8;
  const u16* a0 = A + (m0 + ra) * (long)K + ca;
  const int rb = tid >> 2;
  const int cb0 = ((tid & 3) ^ ((rb >> 1) & 3)) * 8;
  const int cb1 = ((tid & 3) ^ (((rb + 128) >> 1) & 3)) * 8;
  const u16* b0 = Bt + (n0 + rb) * (long)K + cb0;
  const u16* b1 = Bt + (n0 + rb + 128) * (long)K + cb1;

  f32x4 acc[4][4] = {};
  const int NT = K >> 5;

  gll16(a0, (u16*)lA[0] + tid * 8);
  gll16(b0, (u16*)lB[0] + tid * 8);
  gll16(b1, (u16*)lB[0] + 4096 + tid * 8);

  for (int j = 0; j < NT; ++j) {
    const int cur = j & 1;
    const int kk1 = (j + 1) << 5;
    if (j + 1 < NT) {
      gll16(a0 + kk1, (u16*)lA[cur ^ 1] + tid * 8);
      gll16(b0 + kk1, (u16*)lB[cur ^ 1] + tid * 8);
      gll16(b1 + kk1, (u16*)lB[cur ^ 1] + 4096 + tid * 8);
      VMW(3);
    } else {
      VMW(0);
    }
    __builtin_amdgcn_s_barrier();
    FENCE;
    bf16x8 af[4], bfv[4];
    #pragma unroll
    for (int i = 0; i < 4; ++i)
      af[i] = *(const bf16x8*)&lA[cur][(wm + i * 16 + fr) * 32 + ((l4 ^ sw) * 8)];
    #pragma unroll
    for (int jj = 0; jj < 4; ++jj)
      bfv[jj] = *(const bf16x8*)&lB[cur][(wn + jj * 16 + fr) * 32 + ((l4 ^ sw) * 8)];
    #pragma unroll
    for (int i = 0; i < 4; ++i)
      #pragma unroll
      for (int jj = 0; jj < 4; ++jj)
        acc[i][jj] = __builtin_amdgcn_mfma_f32_16x16x32_bf16(af[i], bfv[jj], acc[i][jj], 0, 0, 0);
    FENCE;
    __builtin_amdgcn_s_barrier();
    FENCE;
  }

  const long r0 = m0 + wm + l4 * 4;
  const long c0 = n0 + wn + fr;
  #pragma unroll
  for (int j = 0; j < 4; ++j) {
    long col = c0 + j * 16;
    float bs = bias[col];
    #pragma unroll
    for (int i = 0; i < 4; ++i)
      #pragma unroll
      for (int r = 0; r < 4; ++r)
        C[(r0 + i * 16 + r) * (long)N + col] = acc[i][j][r] + bs;
  }
}

// ---------------- generic bf16 MFMA GEMM, BMxBN tiles, 256 thr (2x2 waves),
// chunk-XOR swizzle (0 conflicts), dbuf + prefetch + counted vmcnt.
// MODE 0: f32 C = acc+bias ; 1: f32 C += acc+bias ; 2: bf16 C = acc+bias ;
// MODE 3: silu-fused (pair-interleaved Bt, BN=128): bf16 gate out [M][2816]
template <int MODE, int BM, int BN>
__global__ __launch_bounds__(256, 4) void k_gemm(
    const u16* __restrict__ A, const u16* __restrict__ Bt,
    const float* __restrict__ bias, void* __restrict__ C,
    int N, int K) {
  constexpr int MI = BM / 32, NJ = BN / 32;
  constexpr int AL = BM / 64, BL = BN / 64;    // gll16 per stage (64-row groups)
  __shared__ u16 lA[2][BM * 32];
  __shared__ u16 lB[2][BN * 32];
  const int tid = threadIdx.x;
  const int gx = gridDim.x;
  const int nwg = gx * gridDim.y;
  const int f = blockIdx.y * gx + blockIdx.x;
  const int f2 = (f & 7) * (nwg >> 3) + (f >> 3);   // xcd swizzle, nwg%8==0
  const int bx = f2 % gx, by = f2 / gx;
  const long m0 = (long)bx * BM, n0 = (long)by * BN;
  const int lane = tid & 63, wid = tid >> 6;
  const int wm = (wid >> 1) * (BM / 2), wn = (wid & 1) * (BN / 2);
  const int fr = lane & 15, l4 = lane >> 4;
  const int sw = (fr >> 1) & 3;

  const int rs = tid >> 2;                            // stage row (per 64-group)
  const int cs = ((tid & 3) ^ ((rs >> 1) & 3)) * 8;   // swizzled chunk (involution)
  const u16* a0 = A + (m0 + rs) * (long)K + cs;
  const u16* b0 = Bt + (n0 + rs) * (long)K + cs;
  const long g64 = 64L * K;

  f32x4 acc[MI][NJ] = {};
  const int NT = K >> 5;

  // each 64-row group = 64 rows x 32 u16 = 2048 LDS elements (R10 bug was 4096)
  auto stage = [&](int buf, int kk) {
    #pragma unroll
    for (int g = 0; g < AL; ++g)
      gll16(a0 + g * g64 + kk, (u16*)lA[buf] + g * 2048 + tid * 8);
    #pragma unroll
    for (int g = 0; g < BL; ++g)
      gll16(b0 + g * g64 + kk, (u16*)lB[buf] + g * 2048 + tid * 8);
  };

  stage(0, 0);

  for (int j = 0; j < NT; ++j) {
    const int cur = j & 1;
    const int kk1 = (j + 1) << 5;
    if (j + 1 < NT) {
      stage(cur ^ 1, kk1);
      if constexpr (AL + BL == 2) VMW(2);
      else if constexpr (AL + BL == 3) VMW(3);
      else VMW(4);
    } else {
      VMW(0);
    }
    __builtin_amdgcn_s_barrier();
    FENCE;
    bf16x8 af[MI], bfr[NJ];
    #pragma unroll
    for (int i = 0; i < MI; i++)
      af[i] = *(const bf16x8*)&lA[cur][(wm + i * 16 + fr) * 32 + ((l4 ^ sw) * 8)];
    #pragma unroll
    for (int jj = 0; jj < NJ; jj++)
      bfr[jj] = *(const bf16x8*)&lB[cur][(wn + jj * 16 + fr) * 32 + ((l4 ^ sw) * 8)];
    #pragma unroll
    for (int i = 0; i < MI; i++)
      #pragma unroll
      for (int jj = 0; jj < NJ; jj++)
        acc[i][jj] = __builtin_amdgcn_mfma_f32_16x16x32_bf16(af[i], bfr[jj], acc[i][jj], 0, 0, 0);
    FENCE;
    __builtin_amdgcn_s_barrier();
    FENCE;
  }

  const long r0 = m0 + wm + l4 * 4;
  const long c0 = n0 + wn + fr;
  if (MODE == 3) {
    u16* G = (u16*)C;
    #pragma unroll
    for (int j = 0; j < NJ; ++j) {
      long col = c0 + j * 16;
      int pcol = (int)((col & 1) ? (col >> 1) + 2816 : (col >> 1));
      float bs = bias[pcol];
      #pragma unroll
      for (int i = 0; i < MI; ++i)
        #pragma unroll
        for (int r = 0; r < 4; ++r) {
          float val = acc[i][j][r] + bs;
          float oth = __shfl_xor(val, 1);
          if (!(col & 1)) {
            float x = oth;
            float gv = val * x * (1.f / (1.f + __expf(-x)));
            G[(r0 + i * 16 + r) * 2816L + (col >> 1)] = f2b(gv);
          }
        }
    }
  } else {
    #pragma unroll
    for (int j = 0; j < NJ; ++j) {
      long col = c0 + j * 16;
      float bs = bias[col];
      #pragma unroll
      for (int i = 0; i < MI; ++i)
        #pragma unroll
        for (int r = 0; r < 4; ++r) {
          long row = r0 + i * 16 + r;
          float val = acc[i][j][r] + bs;
          if (MODE == 0) ((float*)C)[row * N + col] = val;
          else if (MODE == 1) { float* p = (float*)C + row * N + col; *p += val; }
          else ((u16*)C)[row * N + col] = f2b(val);
        }
    }
  }
}

extern "C" void kernel_launch(void* const* d_in, const int* in_sizes, int n_in,
                              void* d_out, int out_size, void* d_ws, size_t ws_size,
                              hipStream_t stream) {
  (void)in_sizes; (void)n_in; (void)out_size; (void)ws_size;
  const int*   tokens    = (const int*)  d_in[0];
  const float* embed     = (const float*)d_in[1];
  const float* w_kv_down = (const float*)d_in[2];
  const float* b_kv_down = (const float*)d_in[3];
  const float* w_q_down  = (const float*)d_in[4];
  const float* b_q_down  = (const float*)d_in[5];
  const float* w_kv_up   = (const float*)d_in[6];
  const float* b_kv_up   = (const float*)d_in[7];
  const float* w_q_up    = (const float*)d_in[8];
  const float* b_q_up    = (const float*)d_in[9];
  const float* w_o       = (const float*)d_in[10];
  const float* b_o       = (const float*)d_in[11];
  const float* kv_norm_w = (const float*)d_in[12];
  const float* q_norm_w  = (const float*)d_in[13];
  const float* norm1_w   = (const float*)d_in[14];
  const float* norm2_w   = (const float*)d_in[15];
  const float* w_in      = (const float*)d_in[16];
  const float* b_in      = (const float*)d_in[17];
  const float* w_out     = (const float*)d_in[18];
  const float* b_out     = (const float*)d_in[19];
  const float* norm_f_w  = (const float*)d_in[20];
  const float* w_head    = (const float*)d_in[21];
  const float* b_head    = (const float*)d_in[22];

  char* base = (char*)d_ws;
  size_t off = 0;
  auto alloc = [&](size_t bytes) -> void* {
    void* p = base + off;
    off += (bytes + 255) & ~(size_t)255;
    return p;
  };
  u16* warena = (u16*)alloc((size_t)32000 * 1024 * 2);
  u16* wT_dq    = warena;                        // 768 x 1024
  u16* wT_kvup  = wT_dq   + 768 * 1024;          // 2048 x 256
  u16* wT_qup   = wT_kvup + 2048 * 256;          // 1536 x 384
  u16* wT_o     = wT_qup  + 1536 * 384;          // 1024 x 1024
  u16* wT_in    = wT_o    + 1024 * 1024;         // 5632 x 1024 (pair-interleaved)
  u16* wT_out   = wT_in   + 5632 * 1024;         // 1024 x 2816

  float* h     = (float*)alloc((size_t)Mm * 1024 * 4);
  u16*   xn    = (u16*)  alloc((size_t)Mm * 1024 * 2);
  float* ckvq  = (float*)alloc((size_t)Mm * 768 * 4);
  float* bdq   = (float*)alloc(768 * 4);
  u16*   ckvn  = (u16*)  alloc((size_t)Mm * 256 * 2);
  u16*   kv    = (u16*)  alloc((size_t)Mm * 2048 * 2);
  u16*   qdn   = (u16*)  alloc((size_t)Mm * 384 * 2);
  float* qf    = (float*)alloc((size_t)Mm * 1536 * 4);
  u16*   Qb    = (u16*)  alloc((size_t)32 * 1024 * QKD * 2);
  u16*   Kb    = (u16*)  alloc((size_t)32 * 1024 * QKD * 2);
  u16*   Vt    = (u16*)  alloc((size_t)32 * 64 * 1024 * 2);
  u16*   attn  = (u16*)  alloc((size_t)Mm * 1024 * 2);
  u16*   gate  = (u16*)  alloc((size_t)Mm * 2816 * 2);

  dim3 tb(32, 8);

  k_embed<<<Mm, 256, 0, stream>>>(tokens, embed, h);

  for (int l = 0; l < 4; l++) {
    WJobs jb;
    jb.j[0] = { w_kv_down + (size_t)l * 1024 * 288,  wT_dq,              1024, 288,  0, 96 };
    jb.j[1] = { w_q_down  + (size_t)l * 1024 * 384,  wT_dq + 384 * 1024, 1024, 384,  0, 96 };
    jb.j[2] = { w_kv_up   + (size_t)l * 256 * 2048,  wT_kvup,            256,  2048, 0, 128 };
    jb.j[3] = { w_q_up    + (size_t)l * 384 * 1536,  wT_qup,             384,  1536, 0, 144 };
    jb.j[4] = { w_o       + (size_t)l * 1024 * 1024, wT_o,               1024, 1024, 0, 256 };
    jb.j[5] = { w_in      + (size_t)l * 1024 * 5632, wT_in,              1024, 5632, 1, 1408 };
    jb.j[6] = { w_out     + (size_t)l * 2816 * 1024, wT_out,             2816, 1024, 0, 704 };
    k_wcvt_batch<<<2832, 256, 0, stream>>>(jb, 7);
    k_biascat<<<3, 256, 0, stream>>>(b_kv_down + l * 288, b_q_down + l * 384, bdq);

    k_rms<<<Mm, 256, 0, stream>>>(h, 1024, norm1_w + l * 1024, xn, 1024);
    // fused kv_down+q_down: 64x64 tiles, grid 32x12 = 384
    k_gemm<0, 64, 64><<<dim3(32, 12), 256, 0, stream>>>(xn, wT_dq, bdq, ckvq, 768, 1024);
    k_rms<<<Mm, 256, 0, stream>>>(ckvq, 768, kv_norm_w + l * 256, ckvn, 256);
    // kv_up -> bf16, 64x128 tiles, grid 32x16 = 512
    k_gemm<2, 64, 128><<<dim3(32, 16), 256, 0, stream>>>(ckvn, wT_kvup, b_kv_up + l * 2048,
                                                         kv, 2048, 256);
    k_rms<<<Mm, 256, 0, stream>>>(ckvq + 384, 768, q_norm_w + l * 384, qdn, 384);
    // q_up: 64x64, grid 32x24 = 768
    k_gemm<0, 64, 64><<<dim3(32, 24), 256, 0, stream>>>(qdn, wT_qup, b_q_up + l * 1536,
                                                        qf, 1536, 384);
    k_buildqk<<<dim3(Ss, 32), 128, 0, stream>>>(qf, kv, ckvq, Qb, Kb);
    k_buildvt<<<dim3(32, 32, 2), tb, 0, stream>>>(kv, Vt);
    k_flash<<<dim3(16, 32), 256, 0, stream>>>(Qb, Kb, Vt, attn);
    // w_o residual: 64x64, grid 32x16 = 512
    k_gemm<1, 64, 64><<<dim3(32, 16), 256, 0, stream>>>(attn, wT_o, b_o + l * 1024,
                                                        h, 1024, 1024);
    k_rms<<<Mm, 256, 0, stream>>>(h, 1024, norm2_w + l * 1024, xn, 1024);
    // w_in + silu: 128x128, grid 16x44 = 704
    k_gemm<3, 128, 128><<<dim3(16, 44), 256, 0, stream>>>(xn, wT_in, b_in + l * 5632,
                                                          gate, 5632, 1024);
    // w_out residual: 64x64, grid 32x16 = 512
    k_gemm<1, 64, 64><<<dim3(32, 16), 256, 0, stream>>>(gate, wT_out, b_out + l * 1024,
                                                        h, 1024, 2816);
  }

  k_rms<<<Mm, 256, 0, stream>>>(h, 1024, norm_f_w, xn, 1024);
  {
    WJobs jbh;
    jbh.j[0] = { w_head, warena, 1024, 32000, 0, 8000 };
    k_wcvt_batch<<<8000, 256, 0, stream>>>(jbh, 1);
  }
  k_gemm256b<<<dim3(16, 125), 512, 0, stream>>>(xn, warena, b_head,
                                                (float*)d_out, 32000, 1024);
}

// Round 12
// 1060.355 us; speedup vs baseline: 2.3151x; 1.0092x over previous
//
#include <hip/hip_runtime.h>
#include <cstdint>
#include <cstddef>

typedef unsigned short u16;
typedef __attribute__((__ext_vector_type__(8))) __bf16 bf16x8;
typedef __attribute__((__ext_vector_type__(4))) float f32x4;
typedef __attribute__((__ext_vector_type__(8))) unsigned short u16x8;

#define DEVI __device__ __forceinline__

constexpr int Bb = 2, Ss = 1024, Dd = 1024, Hh = 16;
constexpr int Mm = Bb * Ss;
constexpr int QKD = 128;
constexpr float EPSF = 1.1920929e-07f;
constexpr float NEG = -1e30f;
constexpr float QSCALE = 0.10206207261596577f; // 1/sqrt(96)
constexpr float LOG1E4_16 = 9.210340371976184f / 16.f;

DEVI u16 f2b(float f) {
  union { float f; uint32_t u; } a; a.f = f;
  uint32_t r = a.u + 0x7FFFu + ((a.u >> 16) & 1u);
  return (u16)(r >> 16);
}
DEVI float b2f(u16 h) {
  union { uint32_t u; float f; } a; a.u = ((uint32_t)h) << 16; return a.f;
}

// ---------------- batched fp32 -> bf16 transposed weight conversion
struct WJob { const float* src; u16* dst; int K; int N; int perm; int ntiles; };
struct WJobs { WJob j[7]; };

__global__ __launch_bounds__(256) void k_wcvt_batch(WJobs jobs, int njobs) {
  int t = blockIdx.x;
  int ji = 0;
  while (ji < njobs - 1 && t >= jobs.j[ji].ntiles) { t -= jobs.j[ji].ntiles; ++ji; }
  const float* __restrict__ src = jobs.j[ji].src;
  u16* __restrict__ dst = jobs.j[ji].dst;
  const int K = jobs.j[ji].K, N = jobs.j[ji].N, perm = jobs.j[ji].perm;
  const int ktiles = K >> 6;
  const int bk = (t % ktiles) * 64;
  const int bn = (t / ktiles) * 64;
  __shared__ float ts[64][65];
  const int tid = threadIdx.x;
  {
    int c4 = tid & 15, r = tid >> 4;
    #pragma unroll
    for (int p = 0; p < 4; ++p) {
      int row = r + p * 16;
      int col = bn + c4 * 4;
      float4 v = make_float4(0.f, 0.f, 0.f, 0.f);
      if (col < N) v = *(const float4*)(src + (size_t)(bk + row) * N + col);
      ts[row][c4 * 4 + 0] = v.x; ts[row][c4 * 4 + 1] = v.y;
      ts[row][c4 * 4 + 2] = v.z; ts[row][c4 * 4 + 3] = v.w;
    }
  }
  __syncthreads();
  {
    int k8 = tid & 7, c = tid >> 3;
    #pragma unroll
    for (int p = 0; p < 2; ++p) {
      int cc = c + p * 32;
      int gcol = bn + cc;
      int row = perm ? ((gcol < 2816) ? (gcol * 2) : ((gcol - 2816) * 2 + 1)) : gcol;
      u16x8 o;
      #pragma unroll
      for (int q = 0; q < 8; ++q) o[q] = f2b(ts[k8 * 8 + q][cc]);
      *(u16x8*)(dst + (size_t)row * K + bk + k8 * 8) = o;
    }
  }
}

// ---------------- embedding gather
__global__ void k_embed(const int* __restrict__ tok, const float* __restrict__ emb,
                        float* __restrict__ h) {
  int m = blockIdx.x;
  int t = tok[m];
  const float4* src = (const float4*)(emb + (size_t)t * Dd);
  float4* dst = (float4*)(h + (size_t)m * Dd);
  dst[threadIdx.x] = src[threadIdx.x];
}

// ---------------- rmsnorm: f32 (stride inStride) -> bf16 (stride K)
__global__ void k_rms(const float* __restrict__ in, int inStride,
                      const float* __restrict__ w, u16* __restrict__ out, int K) {
  int m = blockIdx.x;
  const float* x = in + (size_t)m * inStride;
  float ss = 0.f;
  for (int i = threadIdx.x; i < K; i += 256) { float v = x[i]; ss += v * v; }
  #pragma unroll
  for (int off = 32; off; off >>= 1) ss += __shfl_xor(ss, off);
  __shared__ float red[4];
  if ((threadIdx.x & 63) == 0) red[threadIdx.x >> 6] = ss;
  __syncthreads();
  float r = rsqrtf((red[0] + red[1] + red[2] + red[3]) / (float)K + EPSF);
  for (int i = threadIdx.x; i < K; i += 256)
    out[(size_t)m * K + i] = f2b(x[i] * r * w[i]);
}

// ---------------- build Q and K (rope cols 64..95; Q scaled; pad to 128)
__global__ void k_buildqk(const float* __restrict__ qf, const u16* __restrict__ kv,
                          const float* __restrict__ ckvq, u16* __restrict__ Q,
                          u16* __restrict__ Kb) {
  int s = blockIdx.x, bh = blockIdx.y;
  int b = bh >> 4, h = bh & 15;
  int d = threadIdx.x;
  int m = b * Ss + s;
  int j = d - 64;
  float sn = 0.f, cs = 0.f;
  if (d >= 64 && d < 96) {
    float theta = __expf(-(float)(j & 15) * LOG1E4_16);
    __sincosf((float)s * theta, &sn, &cs);
  }
  const float* qrow = qf + (size_t)m * (Hh * 96) + h * 96;
  float qv = 0.f;
  if (d < 64) qv = qrow[d];
  else if (d < 96) {
    float x = qrow[64 + j], o = qrow[64 + (j ^ 16)];
    qv = x * cs + ((j < 16) ? -o : o) * sn;
  }
  Q[((size_t)bh * Ss + s) * QKD + d] = f2b(qv * QSCALE);
  u16 kvv = 0;
  if (d < 64) kvv = kv[(size_t)m * 2048 + h * 128 + d];
  else if (d < 96) {
    const float* rr = ckvq + (size_t)m * 768 + 256;
    float x = rr[j], o = rr[j ^ 16];
    kvv = f2b(x * cs + ((j < 16) ? -o : o) * sn);
  }
  Kb[((size_t)bh * Ss + s) * QKD + d] = kvv;
}

// ---------------- build V^T (per head: [64][1024]), bf16 in -> bf16 out
__global__ void k_buildvt(const u16* __restrict__ kv, u16* __restrict__ Vt) {
  __shared__ u16 t[32][33];
  int bh = blockIdx.x, s0 = blockIdx.y * 32, d0 = blockIdx.z * 32;
  int b = bh >> 4, h = bh & 15;
  int tx = threadIdx.x, ty = threadIdx.y;
  #pragma unroll
  for (int i = ty; i < 32; i += 8) {
    int s = s0 + i, d = d0 + tx;
    t[i][tx] = kv[(size_t)(b * Ss + s) * 2048 + h * 128 + 64 + d];
  }
  __syncthreads();
  #pragma unroll
  for (int i = ty; i < 32; i += 8) {
    int d = d0 + i, s = s0 + tx;
    Vt[((size_t)bh * 64 + d) * Ss + s] = t[tx][i];
  }
}

#define GAS __attribute__((address_space(1)))
#define LAS __attribute__((address_space(3)))
DEVI void gll16(const void* g, void* l) {
  __builtin_amdgcn_global_load_lds((GAS const void*)g, (LAS void*)l, 16, 0, 0);
}
#define VMW(n) asm volatile("s_waitcnt vmcnt(" #n ")" ::: "memory")
#define FENCE asm volatile("" ::: "memory")

// ---------------- fused flash attention (causal), bf16 in/out
__global__ __launch_bounds__(256) void k_flash(
    const u16* __restrict__ Qg, const u16* __restrict__ Kg,
    const u16* __restrict__ Vtg, u16* __restrict__ attn) {
  __shared__ u16 lK[2][64 * 128];
  __shared__ u16 lV[2][64 * 64];
  __shared__ u16 lP[4][16 * 64];
  const int tid = threadIdx.x;
  const int qt = blockIdx.x, bh = blockIdx.y;
  const int b = bh >> 4, h = bh & 15;
  const int lane = tid & 63, w = tid >> 6;
  const int g = lane >> 4, fr = lane & 15;
  const u16* Qh = Qg + (size_t)bh * Ss * QKD;
  const u16* Kh = Kg + (size_t)bh * Ss * QKD;
  const u16* Vh = Vtg + (size_t)bh * 64 * Ss;

  auto stageKV = [&](int buf, int kt) {
    int r = tid >> 4, c = tid & 15;
    #pragma unroll
    for (int gg = 0; gg < 4; ++gg) {
      int row = gg * 16 + r;
      const u16* src = Kh + (size_t)(kt * 64 + row) * QKD + ((c ^ (row & 7)) * 8);
      gll16(src, (u16*)lK[buf] + gg * 2048 + tid * 8);
    }
    int r2 = tid >> 3, c2 = tid & 7;
    #pragma unroll
    for (int gg = 0; gg < 2; ++gg) {
      int d = gg * 32 + r2;
      const u16* src = Vh + (size_t)d * Ss + kt * 64 + ((c2 ^ (d & 7)) * 8);
      gll16(src, (u16*)lV[buf] + gg * 2048 + tid * 8);
    }
  };

  const int q0 = qt * 64;
  bf16x8 af[4];
  const u16* qrow = Qh + (size_t)(q0 + w * 16 + fr) * QKD + g * 8;
  #pragma unroll
  for (int k4 = 0; k4 < 4; ++k4) af[k4] = *(const bf16x8*)(qrow + k4 * 32);

  f32x4 acc_o[4] = {};
  float mrow = NEG, lrow = 0.f;

  stageKV(0, 0);

  for (int kt = 0; kt <= qt; ++kt) {
    const int cur = kt & 1;
    if (kt < qt) { stageKV(cur ^ 1, kt + 1); VMW(6); }
    else { VMW(0); }
    __builtin_amdgcn_s_barrier();
    FENCE;

    f32x4 accs[4] = {};
    #pragma unroll
    for (int j = 0; j < 4; ++j) {
      #pragma unroll
      for (int k4 = 0; k4 < 4; ++k4) {
        int row = j * 16 + fr;
        int ch = (k4 * 4 + g) ^ (row & 7);
        bf16x8 kf = *(const bf16x8*)&lK[cur][row * 128 + ch * 8];
        accs[j] = __builtin_amdgcn_mfma_f32_16x16x32_bf16(kf, af[k4], accs[j], 0, 0, 0);
      }
    }

    float p[16];
    float tmax = NEG;
    #pragma unroll
    for (int j = 0; j < 4; ++j)
      #pragma unroll
      for (int r = 0; r < 4; ++r) {
        float s = accs[j][r];
        int kloc = j * 16 + 4 * g + r;
        bool valid = (kt < qt) || (kloc <= w * 16 + fr);
        s = valid ? s : NEG;
        p[j * 4 + r] = s;
        tmax = fmaxf(tmax, s);
      }
    tmax = fmaxf(tmax, __shfl_xor(tmax, 16));
    tmax = fmaxf(tmax, __shfl_xor(tmax, 32));
    float mnew = fmaxf(mrow, tmax);
    float scale = __expf(mrow - mnew);
    float tsum = 0.f;
    #pragma unroll
    for (int i = 0; i < 16; ++i) { p[i] = __expf(p[i] - mnew); tsum += p[i]; }
    tsum += __shfl_xor(tsum, 16);
    tsum += __shfl_xor(tsum, 32);
    lrow = lrow * scale + tsum;
    mrow = mnew;

    #pragma unroll
    for (int j = 0; j < 4; ++j)
      #pragma unroll
      for (int t = 0; t < 2; ++t) {
        uint32_t u = (uint32_t)f2b(p[j * 4 + 2 * t]) |
                     ((uint32_t)f2b(p[j * 4 + 2 * t + 1]) << 16);
        int kp = 8 * j + 2 * g + t;
        int ch = kp >> 2, wi = kp & 3;
        ((uint32_t*)lP[w])[fr * 32 + ((ch ^ (fr & 7)) << 2) + wi] = u;
      }

    float sc_q[4];
    #pragma unroll
    for (int r = 0; r < 4; ++r) sc_q[r] = __shfl(scale, 4 * g + r);
    #pragma unroll
    for (int j2 = 0; j2 < 4; ++j2)
      #pragma unroll
      for (int r = 0; r < 4; ++r) acc_o[j2][r] *= sc_q[r];

    #pragma unroll
    for (int ksub = 0; ksub < 2; ++ksub) {
      int chp = (4 * ksub + g) ^ (fr & 7);
      bf16x8 pa = *(const bf16x8*)&((const u16*)lP[w])[fr * 64 + chp * 8];
      #pragma unroll
      for (int j2 = 0; j2 < 4; ++j2) {
        int d = j2 * 16 + fr;
        int chv = (ksub * 4 + g) ^ (d & 7);
        bf16x8 vf = *(const bf16x8*)&lV[cur][d * 64 + chv * 8];
        acc_o[j2] = __builtin_amdgcn_mfma_f32_16x16x32_bf16(pa, vf, acc_o[j2], 0, 0, 0);
      }
    }
    FENCE;
    __builtin_amdgcn_s_barrier();
    FENCE;
  }

  float li[4];
  #pragma unroll
  for (int r = 0; r < 4; ++r) li[r] = 1.f / __shfl(lrow, 4 * g + r);
  #pragma unroll
  for (int j2 = 0; j2 < 4; ++j2)
    #pragma unroll
    for (int r = 0; r < 4; ++r) {
      int q = q0 + w * 16 + 4 * g + r;
      int d = j2 * 16 + fr;
      attn[((size_t)(b * Ss) + q) * Dd + h * 64 + d] = f2b(acc_o[j2][r] * li[r]);
    }
}

// ---------------- generic bf16 MFMA GEMM, BMxBN tiles, 256 thr (2x2 waves),
// chunk-XOR swizzle (0 conflicts), dbuf + prefetch + counted vmcnt.
// MODE 0: f32 C = acc+bias ; 1: f32 C += acc+bias ; 2: bf16 C = acc+bias ;
// MODE 3: silu-fused (pair-interleaved Bt): bf16 gate out [M][2816]
// MODE 4: f32 C = acc + dual-bias (cols 0..287 from bias, 384..767 from bias2)
template <int MODE, int BM, int BN>
__global__ __launch_bounds__(256, 4) void k_gemm(
    const u16* __restrict__ A, const u16* __restrict__ Bt,
    const float* __restrict__ bias, const float* __restrict__ bias2,
    void* __restrict__ C, int N, int K) {
  constexpr int MI = BM / 32, NJ = BN / 32;
  constexpr int AL = BM / 64, BL = BN / 64;    // gll16 per stage (64-row groups)
  __shared__ u16 lA[2][BM * 32];
  __shared__ u16 lB[2][BN * 32];
  const int tid = threadIdx.x;
  const int gx = gridDim.x;
  const int nwg = gx * gridDim.y;
  const int f = blockIdx.y * gx + blockIdx.x;
  const int f2 = (f & 7) * (nwg >> 3) + (f >> 3);   // xcd swizzle, nwg%8==0
  const int bx = f2 % gx, by = f2 / gx;
  const long m0 = (long)bx * BM, n0 = (long)by * BN;
  const int lane = tid & 63, wid = tid >> 6;
  const int wm = (wid >> 1) * (BM / 2), wn = (wid & 1) * (BN / 2);
  const int fr = lane & 15, l4 = lane >> 4;
  const int sw = (fr >> 1) & 3;

  const int rs = tid >> 2;                            // stage row (per 64-group)
  const int cs = ((tid & 3) ^ ((rs >> 1) & 3)) * 8;   // swizzled chunk (involution)
  const u16* a0 = A + (m0 + rs) * (long)K + cs;
  const u16* b0 = Bt + (n0 + rs) * (long)K + cs;
  const long g64 = 64L * K;

  f32x4 acc[MI][NJ] = {};
  const int NT = K >> 5;

  // each 64-row group = 64 rows x 32 u16 = 2048 LDS elements
  auto stage = [&](int buf, int kk) {
    #pragma unroll
    for (int g = 0; g < AL; ++g)
      gll16(a0 + g * g64 + kk, (u16*)lA[buf] + g * 2048 + tid * 8);
    #pragma unroll
    for (int g = 0; g < BL; ++g)
      gll16(b0 + g * g64 + kk, (u16*)lB[buf] + g * 2048 + tid * 8);
  };

  stage(0, 0);

  for (int j = 0; j < NT; ++j) {
    const int cur = j & 1;
    const int kk1 = (j + 1) << 5;
    if (j + 1 < NT) {
      stage(cur ^ 1, kk1);
      if constexpr (AL + BL == 2) VMW(2);
      else if constexpr (AL + BL == 3) VMW(3);
      else VMW(4);
    } else {
      VMW(0);
    }
    __builtin_amdgcn_s_barrier();
    FENCE;
    bf16x8 af[MI], bfr[NJ];
    #pragma unroll
    for (int i = 0; i < MI; i++)
      af[i] = *(const bf16x8*)&lA[cur][(wm + i * 16 + fr) * 32 + ((l4 ^ sw) * 8)];
    #pragma unroll
    for (int jj = 0; jj < NJ; jj++)
      bfr[jj] = *(const bf16x8*)&lB[cur][(wn + jj * 16 + fr) * 32 + ((l4 ^ sw) * 8)];
    #pragma unroll
    for (int i = 0; i < MI; i++)
      #pragma unroll
      for (int jj = 0; jj < NJ; jj++)
        acc[i][jj] = __builtin_amdgcn_mfma_f32_16x16x32_bf16(af[i], bfr[jj], acc[i][jj], 0, 0, 0);
    FENCE;
    __builtin_amdgcn_s_barrier();
    FENCE;
  }

  const long r0 = m0 + wm + l4 * 4;
  const long c0 = n0 + wn + fr;
  if (MODE == 3) {
    u16* G = (u16*)C;
    #pragma unroll
    for (int j = 0; j < NJ; ++j) {
      long col = c0 + j * 16;
      int pcol = (int)((col & 1) ? (col >> 1) + 2816 : (col >> 1));
      float bs = bias[pcol];
      #pragma unroll
      for (int i = 0; i < MI; ++i)
        #pragma unroll
        for (int r = 0; r < 4; ++r) {
          float val = acc[i][j][r] + bs;
          float oth = __shfl_xor(val, 1);
          if (!(col & 1)) {
            float x = oth;
            float gv = val * x * (1.f / (1.f + __expf(-x)));
            G[(r0 + i * 16 + r) * 2816L + (col >> 1)] = f2b(gv);
          }
        }
    }
  } else {
    #pragma unroll
    for (int j = 0; j < NJ; ++j) {
      long col = c0 + j * 16;
      float bs;
      if (MODE == 4)
        bs = (col < 288) ? bias[col] : ((col >= 384) ? bias2[col - 384] : 0.f);
      else
        bs = bias[col];
      #pragma unroll
      for (int i = 0; i < MI; ++i)
        #pragma unroll
        for (int r = 0; r < 4; ++r) {
          long row = r0 + i * 16 + r;
          float val = acc[i][j][r] + bs;
          if (MODE == 0 || MODE == 4) ((float*)C)[row * N + col] = val;
          else if (MODE == 1) { float* p = (float*)C + row * N + col; *p += val; }
          else ((u16*)C)[row * N + col] = f2b(val);
        }
    }
  }
}

extern "C" void kernel_launch(void* const* d_in, const int* in_sizes, int n_in,
                              void* d_out, int out_size, void* d_ws, size_t ws_size,
                              hipStream_t stream) {
  (void)in_sizes; (void)n_in; (void)out_size; (void)ws_size;
  const int*   tokens    = (const int*)  d_in[0];
  const float* embed     = (const float*)d_in[1];
  const float* w_kv_down = (const float*)d_in[2];
  const float* b_kv_down = (const float*)d_in[3];
  const float* w_q_down  = (const float*)d_in[4];
  const float* b_q_down  = (const float*)d_in[5];
  const float* w_kv_up   = (const float*)d_in[6];
  const float* b_kv_up   = (const float*)d_in[7];
  const float* w_q_up    = (const float*)d_in[8];
  const float* b_q_up    = (const float*)d_in[9];
  const float* w_o       = (const float*)d_in[10];
  const float* b_o       = (const float*)d_in[11];
  const float* kv_norm_w = (const float*)d_in[12];
  const float* q_norm_w  = (const float*)d_in[13];
  const float* norm1_w   = (const float*)d_in[14];
  const float* norm2_w   = (const float*)d_in[15];
  const float* w_in      = (const float*)d_in[16];
  const float* b_in      = (const float*)d_in[17];
  const float* w_out     = (const float*)d_in[18];
  const float* b_out     = (const float*)d_in[19];
  const float* norm_f_w  = (const float*)d_in[20];
  const float* w_head    = (const float*)d_in[21];
  const float* b_head    = (const float*)d_in[22];

  char* base = (char*)d_ws;
  size_t off = 0;
  auto alloc = [&](size_t bytes) -> void* {
    void* p = base + off;
    off += (bytes + 255) & ~(size_t)255;
    return p;
  };
  u16* warena = (u16*)alloc((size_t)32000 * 1024 * 2);
  u16* wT_dq    = warena;                        // 768 x 1024
  u16* wT_kvup  = wT_dq   + 768 * 1024;          // 2048 x 256
  u16* wT_qup   = wT_kvup + 2048 * 256;          // 1536 x 384
  u16* wT_o     = wT_qup  + 1536 * 384;          // 1024 x 1024
  u16* wT_in    = wT_o    + 1024 * 1024;         // 5632 x 1024 (pair-interleaved)
  u16* wT_out   = wT_in   + 5632 * 1024;         // 1024 x 2816

  float* h     = (float*)alloc((size_t)Mm * 1024 * 4);
  u16*   xn    = (u16*)  alloc((size_t)Mm * 1024 * 2);
  float* ckvq  = (float*)alloc((size_t)Mm * 768 * 4);
  u16*   ckvn  = (u16*)  alloc((size_t)Mm * 256 * 2);
  u16*   kv    = (u16*)  alloc((size_t)Mm * 2048 * 2);
  u16*   qdn   = (u16*)  alloc((size_t)Mm * 384 * 2);
  float* qf    = (float*)alloc((size_t)Mm * 1536 * 4);
  u16*   Qb    = (u16*)  alloc((size_t)32 * 1024 * QKD * 2);
  u16*   Kb    = (u16*)  alloc((size_t)32 * 1024 * QKD * 2);
  u16*   Vt    = (u16*)  alloc((size_t)32 * 64 * 1024 * 2);
  u16*   attn  = (u16*)  alloc((size_t)Mm * 1024 * 2);
  u16*   gate  = (u16*)  alloc((size_t)Mm * 2816 * 2);

  dim3 tb(32, 8);

  k_embed<<<Mm, 256, 0, stream>>>(tokens, embed, h);

  for (int l = 0; l < 4; l++) {
    WJobs jb;
    jb.j[0] = { w_kv_down + (size_t)l * 1024 * 288,  wT_dq,              1024, 288,  0, 96 };
    jb.j[1] = { w_q_down  + (size_t)l * 1024 * 384,  wT_dq + 384 * 1024, 1024, 384,  0, 96 };
    jb.j[2] = { w_kv_up   + (size_t)l * 256 * 2048,  wT_kvup,            256,  2048, 0, 128 };
    jb.j[3] = { w_q_up    + (size_t)l * 384 * 1536,  wT_qup,             384,  1536, 0, 144 };
    jb.j[4] = { w_o       + (size_t)l * 1024 * 1024, wT_o,               1024, 1024, 0, 256 };
    jb.j[5] = { w_in      + (size_t)l * 1024 * 5632, wT_in,              1024, 5632, 1, 1408 };
    jb.j[6] = { w_out     + (size_t)l * 2816 * 1024, wT_out,             2816, 1024, 0, 704 };
    k_wcvt_batch<<<2832, 256, 0, stream>>>(jb, 7);

    k_rms<<<Mm, 256, 0, stream>>>(h, 1024, norm1_w + l * 1024, xn, 1024);
    // fused kv_down+q_down with dual bias (MODE 4): 64x64 tiles, grid 32x12
    k_gemm<4, 64, 64><<<dim3(32, 12), 256, 0, stream>>>(xn, wT_dq, b_kv_down + l * 288,
                                                        b_q_down + l * 384, ckvq, 768, 1024);
    k_rms<<<Mm, 256, 0, stream>>>(ckvq, 768, kv_norm_w + l * 256, ckvn, 256);
    // kv_up -> bf16, 64x128 tiles, grid 32x16
    k_gemm<2, 64, 128><<<dim3(32, 16), 256, 0, stream>>>(ckvn, wT_kvup, b_kv_up + l * 2048,
                                                         nullptr, kv, 2048, 256);
    k_rms<<<Mm, 256, 0, stream>>>(ckvq + 384, 768, q_norm_w + l * 384, qdn, 384);
    // q_up: 64x64, grid 32x24
    k_gemm<0, 64, 64><<<dim3(32, 24), 256, 0, stream>>>(qdn, wT_qup, b_q_up + l * 1536,
                                                        nullptr, qf, 1536, 384);
    k_buildqk<<<dim3(Ss, 32), 128, 0, stream>>>(qf, kv, ckvq, Qb, Kb);
    k_buildvt<<<dim3(32, 32, 2), tb, 0, stream>>>(kv, Vt);
    k_flash<<<dim3(16, 32), 256, 0, stream>>>(Qb, Kb, Vt, attn);
    // w_o residual: 64x64, grid 32x16
    k_gemm<1, 64, 64><<<dim3(32, 16), 256, 0, stream>>>(attn, wT_o, b_o + l * 1024,
                                                        nullptr, h, 1024, 1024);
    k_rms<<<Mm, 256, 0, stream>>>(h, 1024, norm2_w + l * 1024, xn, 1024);
    // w_in + silu: 128x128, grid 16x44
    k_gemm<3, 128, 128><<<dim3(16, 44), 256, 0, stream>>>(xn, wT_in, b_in + l * 5632,
                                                          nullptr, gate, 5632, 1024);
    // w_out residual: 64x64, grid 32x16
    k_gemm<1, 64, 64><<<dim3(32, 16), 256, 0, stream>>>(gate, wT_out, b_out + l * 1024,
                                                        nullptr, h, 1024, 2816);
  }

  k_rms<<<Mm, 256, 0, stream>>>(h, 1024, norm_f_w, xn, 1024);
  {
    WJobs jbh;
    jbh.j[0] = { w_head, warena, 1024, 32000, 0, 8000 };
    k_wcvt_batch<<<8000, 256, 0, stream>>>(jbh, 1);
  }
  // head: 128x128 tiles, grid 16x250 = 4000 blocks (4 blocks/CU resident)
  k_gemm<0, 128, 128><<<dim3(16, 250), 256, 0, stream>>>(xn, warena, b_head,
                                                         nullptr, (float*)d_out, 32000, 1024);
}